// Round 2
// baseline (4611.106 us; speedup 1.0000x reference)
//
#include <hip/hip_runtime.h>
#include <cfloat>

#define N_TOK   32768
#define K_CODES 8192
#define D_DIM   256
#define TM      64      // tokens per tile
#define TK      256     // codes per k-chunk
#define TD      16      // d per LDS stage
#define CTAU    4.5e-5f // contested if fp32 top-2 gap below this (> ulp(d)=3.05e-5 + slack)
#define CAND_M  3.5e-5f // candidate margin vs per-token min (ulp + emulation/accum slack)
#define MAXCAND 24

// ws layout (bytes):
//   0      : double   loss_sum
//   8      : unsigned contested_count (+4 pad)
//   16     : float e2np[8192]     np-exact fp32 ||e||^2        (32 KB)
//   32784  : float Cnp[32768]     np-exact fp32 ||z||^2 rows   (128 KB)
//   163856 : float s1f[32768]     bulk fp32 min score          (128 KB)
//   294928 : int   idxf[32768]    final indices                (128 KB)
//   426000 : int   clist[32768]   contested token list         (128 KB)

// ======== numpy bit-exact fp32 emulation helpers (NO fma contraction) ========

// np.sum(x*x, axis=1) for a 256-elem row: pairwise_sum -> 128+128 blocks,
// each block: 8 scalar accumulators, combine ((r0+r1)+(r2+r3))+((r4+r5)+(r6+r7))
__device__ __forceinline__ float np_sumsq256(const float* __restrict__ row) {
    #pragma clang fp contract(off)
    float blk[2];
    #pragma unroll
    for (int b = 0; b < 2; b++) {
        const float* x = row + b * 128;
        float r[8];
        #pragma unroll
        for (int j = 0; j < 8; j++) { float v = x[j]; r[j] = v * v; }
        for (int i = 8; i < 128; i += 8) {
            #pragma unroll
            for (int j = 0; j < 8; j++) { float v = x[i + j]; r[j] += v * v; }
        }
        blk[b] = ((r[0] + r[1]) + (r[2] + r[3])) + ((r[4] + r[5]) + (r[6] + r[7]));
    }
    return blk[0] + blk[1];
}

// np.einsum('nd,kd->nk') fp32 inner kernel (sum_of_products_contig_outstride0_two,
// baseline SSE no-FMA): per 16 elems, lane l: A_l = p0 + (p1 + (p2 + (p3 + A_l)));
// final npyv_sum_f32 (SSE3 hadd): (A0+A1)+(A2+A3).
__device__ __forceinline__ float np_einsum256(const float* __restrict__ a,
                                              const float* __restrict__ b) {
    #pragma clang fp contract(off)
    float A0 = 0.f, A1 = 0.f, A2 = 0.f, A3 = 0.f;
    for (int m = 0; m < 256; m += 16) {
        A0 = a[m+ 0]*b[m+ 0] + (a[m+ 4]*b[m+ 4] + (a[m+ 8]*b[m+ 8] + (a[m+12]*b[m+12] + A0)));
        A1 = a[m+ 1]*b[m+ 1] + (a[m+ 5]*b[m+ 5] + (a[m+ 9]*b[m+ 9] + (a[m+13]*b[m+13] + A1)));
        A2 = a[m+ 2]*b[m+ 2] + (a[m+ 6]*b[m+ 6] + (a[m+10]*b[m+10] + (a[m+14]*b[m+14] + A2)));
        A3 = a[m+ 3]*b[m+ 3] + (a[m+ 7]*b[m+ 7] + (a[m+11]*b[m+11] + (a[m+15]*b[m+15] + A3)));
    }
    return (A0 + A1) + (A2 + A3);
}

// d = fl(fl(C + e2) - 2*g)   (2*g exact doubling; each op rounded once, like np)
__device__ __forceinline__ float np_dtilde(float Cn, float e2k, float g) {
    #pragma clang fp contract(off)
    float t = Cn + e2k;
    float d = t - 2.0f * g;
    return d;
}

// ---------------- kernel 1a: codebook norms (np-exact) + counter init ----------------
__global__ __launch_bounds__(256) void prep_e_kernel(
    const float* __restrict__ emb, float* __restrict__ e2np,
    unsigned* __restrict__ ccount, double* __restrict__ loss_sum)
{
    int k = blockIdx.x * 256 + threadIdx.x;   // 32 blocks
    e2np[k] = np_sumsq256(emb + (size_t)k * D_DIM);
    if (k == 0) { *ccount = 0u; *loss_sum = 0.0; }
}

// ---------------- kernel 1b: token norms (np-exact) ----------------
__global__ __launch_bounds__(256) void prep_z_kernel(
    const float* __restrict__ z, float* __restrict__ Cnp)
{
    int t = blockIdx.x * 256 + threadIdx.x;   // 128 blocks
    Cnp[t] = np_sumsq256(z + (size_t)t * D_DIM);
}

// ---------------- kernel 2: bulk fp32 distance scan + top-2 ----------------
__global__ __launch_bounds__(256) void bulk_kernel(
    const float* __restrict__ z, const float* __restrict__ emb,
    const float* __restrict__ enf, int* __restrict__ idxf,
    float* __restrict__ s1f, int* __restrict__ clist,
    unsigned* __restrict__ ccount)
{
    __shared__ __align__(16) float zs[TD][TM + 4];
    __shared__ __align__(16) float es[TD][TK + 4];
    const int tid = threadIdx.x;
    const int tg  = tid >> 5;
    const int cg  = tid & 31;
    const size_t t0 = (size_t)blockIdx.x * TM;

    float s1[8], s2[8]; int i1[8];
    #pragma unroll
    for (int i = 0; i < 8; i++) { s1[i] = FLT_MAX; s2[i] = FLT_MAX; i1[i] = 0x7fffffff; }

    for (int kc = 0; kc < K_CODES; kc += TK) {
        float acc[8][8];
        #pragma unroll
        for (int i = 0; i < 8; i++)
            #pragma unroll
            for (int j = 0; j < 8; j++) acc[i][j] = 0.f;

        for (int d0 = 0; d0 < D_DIM; d0 += TD) {
            const float4* ep = (const float4*)(emb + (size_t)(kc + tid) * D_DIM + d0);
            float4 e0 = ep[0], e1 = ep[1], e2 = ep[2], e3 = ep[3];
            float4 z0 = make_float4(0.f,0.f,0.f,0.f), z1 = z0, z2 = z0, z3 = z0;
            if (tid < TM) {
                const float4* zp = (const float4*)(z + (t0 + tid) * D_DIM + d0);
                z0 = zp[0]; z1 = zp[1]; z2 = zp[2]; z3 = zp[3];
            }
            __syncthreads();
            es[ 0][tid] = e0.x; es[ 1][tid] = e0.y; es[ 2][tid] = e0.z; es[ 3][tid] = e0.w;
            es[ 4][tid] = e1.x; es[ 5][tid] = e1.y; es[ 6][tid] = e1.z; es[ 7][tid] = e1.w;
            es[ 8][tid] = e2.x; es[ 9][tid] = e2.y; es[10][tid] = e2.z; es[11][tid] = e2.w;
            es[12][tid] = e3.x; es[13][tid] = e3.y; es[14][tid] = e3.z; es[15][tid] = e3.w;
            if (tid < TM) {
                zs[ 0][tid] = z0.x; zs[ 1][tid] = z0.y; zs[ 2][tid] = z0.z; zs[ 3][tid] = z0.w;
                zs[ 4][tid] = z1.x; zs[ 5][tid] = z1.y; zs[ 6][tid] = z1.z; zs[ 7][tid] = z1.w;
                zs[ 8][tid] = z2.x; zs[ 9][tid] = z2.y; zs[10][tid] = z2.z; zs[11][tid] = z2.w;
                zs[12][tid] = z3.x; zs[13][tid] = z3.y; zs[14][tid] = z3.z; zs[15][tid] = z3.w;
            }
            __syncthreads();
            #pragma unroll
            for (int dd = 0; dd < TD; dd++) {
                float4 za = *(const float4*)(&zs[dd][tg * 4]);
                float4 zb = *(const float4*)(&zs[dd][32 + tg * 4]);
                float4 ea = *(const float4*)(&es[dd][cg * 4]);
                float4 eb = *(const float4*)(&es[dd][128 + cg * 4]);
                float zr[8] = {za.x, za.y, za.z, za.w, zb.x, zb.y, zb.z, zb.w};
                float er[8] = {ea.x, ea.y, ea.z, ea.w, eb.x, eb.y, eb.z, eb.w};
                #pragma unroll
                for (int i = 0; i < 8; i++)
                    #pragma unroll
                    for (int j = 0; j < 8; j++)
                        acc[i][j] = fmaf(zr[i], er[j], acc[i][j]);
            }
        }
        #pragma unroll
        for (int j = 0; j < 8; j++) {
            const int code = kc + ((j < 4) ? (cg * 4 + j) : (128 + cg * 4 + (j - 4)));
            const float en = enf[code];
            #pragma unroll
            for (int i = 0; i < 8; i++) {
                float s = fmaf(-2.f, acc[i][j], en);
                if (s < s1[i]) { s2[i] = s1[i]; s1[i] = s; i1[i] = code; }
                else if (s < s2[i]) { s2[i] = s; }
            }
        }
    }

    #pragma unroll
    for (int off = 16; off >= 1; off >>= 1) {
        #pragma unroll
        for (int i = 0; i < 8; i++) {
            float b1 = __shfl_xor(s1[i], off);
            float b2 = __shfl_xor(s2[i], off);
            int   bi = __shfl_xor(i1[i], off);
            bool take = (b1 < s1[i]) || (b1 == s1[i] && bi < i1[i]);
            float w1 = take ? b1 : s1[i];
            int   wi = take ? bi : i1[i];
            float l1 = take ? s1[i] : b1;
            s2[i] = fminf(fminf(s2[i], b2), l1);
            s1[i] = w1; i1[i] = wi;
        }
    }
    if (cg == 0) {
        #pragma unroll
        for (int i = 0; i < 8; i++) {
            int trow = (i < 4) ? (tg * 4 + i) : (32 + tg * 4 + (i - 4));
            int t = (int)t0 + trow;
            idxf[t] = i1[i];
            s1f[t]  = s1[i];
            if (s2[i] - s1[i] < CTAU) {
                unsigned p = atomicAdd(ccount, 1u);
                clist[p] = t;
            }
        }
    }
}

// ---------------- kernel 3: contested re-sweep + np-exact tie resolution ----------------
// Processes 64 contested tokens per block: full fp32 re-scan collecting all codes
// within CAND_M of the bulk min, then emulates numpy's fp32 d for those candidates
// and picks the first-index min (== np.argmin on float32 d).
__global__ __launch_bounds__(256) void rescue_kernel(
    const float* __restrict__ z, const float* __restrict__ emb,
    const float* __restrict__ enf, const float* __restrict__ Cnp,
    const float* __restrict__ s1f, const unsigned* __restrict__ ccount,
    const int* __restrict__ clist, int* __restrict__ idxf)
{
    const unsigned count = *ccount;
    const unsigned base  = blockIdx.x * TM;
    if (base >= count) return;
    const int nt = (int)min((unsigned)TM, count - base);

    __shared__ __align__(16) float zs[TD][TM + 4];
    __shared__ __align__(16) float es[TD][TK + 4];
    __shared__ int      tlist[TM];
    __shared__ unsigned ccnt[TM];
    __shared__ int      cand[TM][MAXCAND];

    const int tid = threadIdx.x;
    const int tg  = tid >> 5;
    const int cg  = tid & 31;

    if (tid < TM) {
        tlist[tid] = clist[base + ((tid < nt) ? tid : 0)];
        ccnt[tid]  = 0u;
    }
    __syncthreads();

    const int mytok = (tid < TM) ? tlist[tid] : 0;
    float thr[8];
    #pragma unroll
    for (int i = 0; i < 8; i++) {
        int trow = (i < 4) ? (tg * 4 + i) : (32 + tg * 4 + (i - 4));
        thr[i] = (trow < nt) ? (s1f[tlist[trow]] + CAND_M) : -FLT_MAX;
    }

    for (int kc = 0; kc < K_CODES; kc += TK) {
        float acc[8][8];
        #pragma unroll
        for (int i = 0; i < 8; i++)
            #pragma unroll
            for (int j = 0; j < 8; j++) acc[i][j] = 0.f;

        for (int d0 = 0; d0 < D_DIM; d0 += TD) {
            const float4* ep = (const float4*)(emb + (size_t)(kc + tid) * D_DIM + d0);
            float4 e0 = ep[0], e1 = ep[1], e2 = ep[2], e3 = ep[3];
            float4 z0 = make_float4(0.f,0.f,0.f,0.f), z1 = z0, z2 = z0, z3 = z0;
            if (tid < TM) {
                const float4* zp = (const float4*)(z + (size_t)mytok * D_DIM + d0);
                z0 = zp[0]; z1 = zp[1]; z2 = zp[2]; z3 = zp[3];
            }
            __syncthreads();
            es[ 0][tid] = e0.x; es[ 1][tid] = e0.y; es[ 2][tid] = e0.z; es[ 3][tid] = e0.w;
            es[ 4][tid] = e1.x; es[ 5][tid] = e1.y; es[ 6][tid] = e1.z; es[ 7][tid] = e1.w;
            es[ 8][tid] = e2.x; es[ 9][tid] = e2.y; es[10][tid] = e2.z; es[11][tid] = e2.w;
            es[12][tid] = e3.x; es[13][tid] = e3.y; es[14][tid] = e3.z; es[15][tid] = e3.w;
            if (tid < TM) {
                zs[ 0][tid] = z0.x; zs[ 1][tid] = z0.y; zs[ 2][tid] = z0.z; zs[ 3][tid] = z0.w;
                zs[ 4][tid] = z1.x; zs[ 5][tid] = z1.y; zs[ 6][tid] = z1.z; zs[ 7][tid] = z1.w;
                zs[ 8][tid] = z2.x; zs[ 9][tid] = z2.y; zs[10][tid] = z2.z; zs[11][tid] = z2.w;
                zs[12][tid] = z3.x; zs[13][tid] = z3.y; zs[14][tid] = z3.z; zs[15][tid] = z3.w;
            }
            __syncthreads();
            #pragma unroll
            for (int dd = 0; dd < TD; dd++) {
                float4 za = *(const float4*)(&zs[dd][tg * 4]);
                float4 zb = *(const float4*)(&zs[dd][32 + tg * 4]);
                float4 ea = *(const float4*)(&es[dd][cg * 4]);
                float4 eb = *(const float4*)(&es[dd][128 + cg * 4]);
                float zr[8] = {za.x, za.y, za.z, za.w, zb.x, zb.y, zb.z, zb.w};
                float er[8] = {ea.x, ea.y, ea.z, ea.w, eb.x, eb.y, eb.z, eb.w};
                #pragma unroll
                for (int i = 0; i < 8; i++)
                    #pragma unroll
                    for (int j = 0; j < 8; j++)
                        acc[i][j] = fmaf(zr[i], er[j], acc[i][j]);
            }
        }
        #pragma unroll
        for (int j = 0; j < 8; j++) {
            const int code = kc + ((j < 4) ? (cg * 4 + j) : (128 + cg * 4 + (j - 4)));
            const float en = enf[code];
            #pragma unroll
            for (int i = 0; i < 8; i++) {
                float s = fmaf(-2.f, acc[i][j], en);
                if (s <= thr[i]) {
                    int trow = (i < 4) ? (tg * 4 + i) : (32 + tg * 4 + (i - 4));
                    unsigned p = atomicAdd(&ccnt[trow], 1u);
                    if (p < MAXCAND) cand[trow][p] = code;
                }
            }
        }
    }
    __syncthreads();

    // phase 2: np-exact d for each candidate; first-index min. One wave per 16 slots.
    const int wave = tid >> 6;
    const int lane = tid & 63;
    for (int s = wave * 16; s < wave * 16 + 16; s++) {
        if (s >= nt) continue;
        const int t = tlist[s];
        const int n = (int)min(ccnt[s], (unsigned)MAXCAND);
        float bd = FLT_MAX; int bk = 0x7fffffff;
        if (lane < n) {
            const int k = cand[s][lane];
            float g = np_einsum256(z + (size_t)t * D_DIM, emb + (size_t)k * D_DIM);
            bd = np_dtilde(Cnp[t], enf[k], g);
            bk = k;
        }
        #pragma unroll
        for (int off = 32; off >= 1; off >>= 1) {
            float od = __shfl_xor(bd, off);
            int   ok = __shfl_xor(bk, off);
            if (od < bd || (od == bd && ok < bk)) { bd = od; bk = ok; }
        }
        if (lane == 0 && n > 0) idxf[t] = bk;
    }
}

// ---------------- kernel 4: gather z_q, write out0, fp64 MSE sum ----------------
__global__ __launch_bounds__(256) void out_loss_kernel(
    const float* __restrict__ z, const float* __restrict__ emb,
    const int* __restrict__ idxf, float* __restrict__ out0,
    double* __restrict__ loss_sum)
{
    const int total4 = N_TOK * (D_DIM / 4);
    double lsum = 0.0;
    for (int p = blockIdx.x * 256 + threadIdx.x; p < total4; p += gridDim.x * 256) {
        const int n  = p >> 6;
        const int d4 = p & 63;
        const int k  = idxf[n];
        float4 zv = ((const float4*)z)[p];
        float4 ev = ((const float4*)(emb + (size_t)k * D_DIM))[d4];
        float dx = ev.x - zv.x, dy = ev.y - zv.y,
              dz = ev.z - zv.z, dw = ev.w - zv.w;
        float4 o;
        o.x = zv.x + dx; o.y = zv.y + dy; o.z = zv.z + dz; o.w = zv.w + dw;
        ((float4*)out0)[p] = o;
        lsum += (double)dx * dx + (double)dy * dy
              + (double)dz * dz + (double)dw * dw;
    }
    #pragma unroll
    for (int off = 32; off >= 1; off >>= 1) lsum += __shfl_xor(lsum, off);
    __shared__ double wsum[4];
    const int wv = threadIdx.x >> 6;
    if ((threadIdx.x & 63) == 0) wsum[wv] = lsum;
    __syncthreads();
    if (threadIdx.x == 0)
        atomicAdd(loss_sum, wsum[0] + wsum[1] + wsum[2] + wsum[3]);
}

// ---------------- kernel 5: scalars + idx as float ----------------
__global__ __launch_bounds__(256) void finalize_kernel(
    const int* __restrict__ idxf, const double* __restrict__ loss_sum,
    float* __restrict__ out)
{
    const int t = blockIdx.x * 256 + threadIdx.x;
    if (t < N_TOK) out[8388611 + t] = (float)idxf[t];
    if (t == 0) {
        double mse = *loss_sum * (1.0 / 8388608.0);
        out[8388608] = (float)(1.25 * mse);
        out[8388609] = (float)(0.25 * mse);
        out[8388610] = (float)mse;
    }
}

extern "C" void kernel_launch(void* const* d_in, const int* in_sizes, int n_in,
                              void* d_out, int out_size, void* d_ws, size_t ws_size,
                              hipStream_t stream)
{
    const float* z   = (const float*)d_in[0];
    const float* emb = (const float*)d_in[1];
    float* out = (float*)d_out;
    char*  ws  = (char*)d_ws;

    double*   loss_sum = (double*)(ws + 0);
    unsigned* ccount   = (unsigned*)(ws + 8);
    float*    e2np     = (float*)(ws + 16);
    float*    Cnp      = (float*)(ws + 32784);
    float*    s1f      = (float*)(ws + 163856);
    int*      idxf     = (int*)(ws + 294928);
    int*      clist    = (int*)(ws + 426000);

    prep_e_kernel<<<dim3(K_CODES / 256), dim3(256), 0, stream>>>(
        emb, e2np, ccount, loss_sum);
    prep_z_kernel<<<dim3(N_TOK / 256), dim3(256), 0, stream>>>(z, Cnp);
    bulk_kernel<<<dim3(N_TOK / TM), dim3(256), 0, stream>>>(
        z, emb, e2np, idxf, s1f, clist, ccount);
    rescue_kernel<<<dim3(N_TOK / TM), dim3(256), 0, stream>>>(
        z, emb, e2np, Cnp, s1f, ccount, clist, idxf);
    out_loss_kernel<<<dim3(1024), dim3(256), 0, stream>>>(
        z, emb, idxf, out, loss_sum);
    finalize_kernel<<<dim3(N_TOK / 256), dim3(256), 0, stream>>>(
        idxf, loss_sum, out);
}

// Round 4
// 2699.020 us; speedup vs baseline: 1.7084x; 1.7084x over previous
//
#include <hip/hip_runtime.h>
#include <cfloat>

#define N_TOK   32768
#define K_CODES 8192
#define D_DIM   256
#define BTOK    128        // tokens per bulk/rescue block
#define CHUNK   128        // codes per chunk
#define NSPLIT  2          // code-range splits in bulk
#define SPLITK  (K_CODES / NSPLIT)
#define DSTG    32         // d per LDS stage
#define LSTR    36         // LDS row stride in shorts (bank-conflict pad)
#define CTAU_M  3.0e-5f    // contested if (m1-m2) < this (acc units; s-gap = 2x)
#define CAND_MM 2.4e-5f    // rescue candidate window (acc units; 4.8e-5 in s)
#define MAXCAND 24

typedef __attribute__((ext_vector_type(4)))  short bf16x4;
typedef __attribute__((ext_vector_type(8)))  short bf16x8;
typedef __attribute__((ext_vector_type(16))) float f32x16;

// ws layout (bytes):
//   0       double   loss_sum
//   8       unsigned ccount
//   16      float e2np[8192]      np-exact fp32 ||e||^2
//   32784   float Cnp[32768]      np-exact fp32 ||z||^2
//   163856  float m1f[32768]      merged max-acc per token
//   294928  int   idxf[32768]
//   426000  int   clist[32768]
//   557072  float m1a[32768*2]    per-split top1 acc
//   819216  float m2a[32768*2]    per-split top2 acc
//   1081360 int   i1a[32768*2]    per-split argmax code

// ======== numpy bit-exact fp32 emulation (NO fma contraction) ========
__device__ __forceinline__ float np_sumsq256(const float* __restrict__ row) {
    #pragma clang fp contract(off)
    float blk[2];
    #pragma unroll
    for (int b = 0; b < 2; b++) {
        const float* x = row + b * 128;
        float r[8];
        #pragma unroll
        for (int j = 0; j < 8; j++) { float v = x[j]; r[j] = v * v; }
        for (int i = 8; i < 128; i += 8) {
            #pragma unroll
            for (int j = 0; j < 8; j++) { float v = x[i + j]; r[j] += v * v; }
        }
        blk[b] = ((r[0] + r[1]) + (r[2] + r[3])) + ((r[4] + r[5]) + (r[6] + r[7]));
    }
    return blk[0] + blk[1];
}

__device__ __forceinline__ float np_einsum256(const float* __restrict__ a,
                                              const float* __restrict__ b) {
    #pragma clang fp contract(off)
    float A0 = 0.f, A1 = 0.f, A2 = 0.f, A3 = 0.f;
    for (int m = 0; m < 256; m += 16) {
        A0 = a[m+ 0]*b[m+ 0] + (a[m+ 4]*b[m+ 4] + (a[m+ 8]*b[m+ 8] + (a[m+12]*b[m+12] + A0)));
        A1 = a[m+ 1]*b[m+ 1] + (a[m+ 5]*b[m+ 5] + (a[m+ 9]*b[m+ 9] + (a[m+13]*b[m+13] + A1)));
        A2 = a[m+ 2]*b[m+ 2] + (a[m+ 6]*b[m+ 6] + (a[m+10]*b[m+10] + (a[m+14]*b[m+14] + A2)));
        A3 = a[m+ 3]*b[m+ 3] + (a[m+ 7]*b[m+ 7] + (a[m+11]*b[m+11] + (a[m+15]*b[m+15] + A3)));
    }
    return (A0 + A1) + (A2 + A3);
}

__device__ __forceinline__ float np_dtilde(float Cn, float e2k, float g) {
    #pragma clang fp contract(off)
    float t = Cn + e2k;
    float d = t - 2.0f * g;
    return d;
}

// ======== bf16 split helpers ========
__device__ __forceinline__ unsigned short bf16_rne(float f) {
    unsigned u = __float_as_uint(f);
    unsigned r = u + 0x7fffu + ((u >> 16) & 1u);
    return (unsigned short)(r >> 16);
}
__device__ __forceinline__ float bf16_f(unsigned short h) {
    return __uint_as_float(((unsigned)h) << 16);
}
__device__ __forceinline__ void split_bf16(float f, short& hi, short& lo) {
    unsigned short h = bf16_rne(f);
    hi = (short)h;
    lo = (short)bf16_rne(f - bf16_f(h));
}

__device__ __forceinline__ bf16x8 rd8(const short* p) {
    bf16x8 v;
    *(bf16x4*)&v       = *(const bf16x4*)p;
    *((bf16x4*)&v + 1) = *(const bf16x4*)(p + 4);
    return v;
}
__device__ __forceinline__ void wr4(short* hi, short* lo, int idx, float4 v) {
    short h0, l0, h1, l1, h2, l2, h3, l3;
    split_bf16(v.x, h0, l0); split_bf16(v.y, h1, l1);
    split_bf16(v.z, h2, l2); split_bf16(v.w, h3, l3);
    bf16x4 vh = {h0, h1, h2, h3};
    bf16x4 vl = {l0, l1, l2, l3};
    *(bf16x4*)&hi[idx] = vh;
    *(bf16x4*)&lo[idx] = vl;
}

#define MFMA3(A, ah, al, bh, bl) \
    A = __builtin_amdgcn_mfma_f32_32x32x16_bf16(ah, bh, A, 0, 0, 0); \
    A = __builtin_amdgcn_mfma_f32_32x32x16_bf16(ah, bl, A, 0, 0, 0); \
    A = __builtin_amdgcn_mfma_f32_32x32x16_bf16(al, bh, A, 0, 0, 0);

// 12 mfma per kstep: acc[tc][tt] += e_tile(tc) x z_tile(tt), split 3-term
__device__ __forceinline__ void do_ksteps(
    int nks, const short* zs_hi, const short* zs_lo,
    const short* es_hi, const short* es_lo,
    f32x16 acc[2][2], int wt, int wc, int lane)
{
    const int half8 = ((lane >> 5) << 3);
    const int arow = (wc * 64 + (lane & 31)) * LSTR + half8;
    const int brow = (wt * 64 + (lane & 31)) * LSTR + half8;
    for (int ks = 0; ks < nks; ks++) {
        const int ko = ks * 16;
        bf16x8 a0h = rd8(&es_hi[arow + ko]);
        bf16x8 a0l = rd8(&es_lo[arow + ko]);
        bf16x8 a1h = rd8(&es_hi[arow + 32 * LSTR + ko]);
        bf16x8 a1l = rd8(&es_lo[arow + 32 * LSTR + ko]);
        bf16x8 b0h = rd8(&zs_hi[brow + ko]);
        bf16x8 b0l = rd8(&zs_lo[brow + ko]);
        bf16x8 b1h = rd8(&zs_hi[brow + 32 * LSTR + ko]);
        bf16x8 b1l = rd8(&zs_lo[brow + 32 * LSTR + ko]);
        MFMA3(acc[0][0], a0h, a0l, b0h, b0l);
        MFMA3(acc[0][1], a0h, a0l, b1h, b1l);
        MFMA3(acc[1][0], a1h, a1l, b0h, b0l);
        MFMA3(acc[1][1], a1h, a1l, b1h, b1l);
    }
}

// ---------------- prep kernels ----------------
__global__ __launch_bounds__(256) void prep_e_kernel(
    const float* __restrict__ emb, float* __restrict__ e2np,
    unsigned* __restrict__ ccount, double* __restrict__ loss_sum)
{
    int k = blockIdx.x * 256 + threadIdx.x;
    e2np[k] = np_sumsq256(emb + (size_t)k * D_DIM);
    if (k == 0) { *ccount = 0u; *loss_sum = 0.0; }
}

__global__ __launch_bounds__(256) void prep_z_kernel(
    const float* __restrict__ z, float* __restrict__ Cnp)
{
    int t = blockIdx.x * 256 + threadIdx.x;
    Cnp[t] = np_sumsq256(z + (size_t)t * D_DIM);
}

// ---------------- bulk mfma scan: 128 tok x 4096 codes per block ----------------
__global__ __launch_bounds__(256, 3) void bulk_kernel(
    const float* __restrict__ z, const float* __restrict__ emb,
    const float* __restrict__ e2np,
    float* __restrict__ m1a, float* __restrict__ m2a, int* __restrict__ i1a)
{
    __shared__ __align__(16) short zs_hi[BTOK * LSTR], zs_lo[BTOK * LSTR];
    __shared__ __align__(16) short es_hi[CHUNK * LSTR], es_lo[CHUNK * LSTR];
    __shared__ float s1m[BTOK], s2m[BTOK];
    __shared__ int   i1m[BTOK];

    const int tid  = threadIdx.x;
    const int lane = tid & 63;
    const int w    = tid >> 6;
    const int wt   = w & 1, wc = w >> 1;
    const int g     = blockIdx.x & 255;
    const int split = blockIdx.x >> 8;
    const int tok0  = g * BTOK;
    const int cs0   = split * SPLITK;

    float m1[2] = {-FLT_MAX, -FLT_MAX}, m2[2] = {-FLT_MAX, -FLT_MAX};
    int   k1[2] = {0x7fffffff, 0x7fffffff};

    for (int c = 0; c < SPLITK / CHUNK; c++) {
        const int code0 = cs0 + c * CHUNK;
        f32x16 acc[2][2];
        #pragma unroll
        for (int i = 0; i < 2; i++)
            #pragma unroll
            for (int j = 0; j < 2; j++)
                #pragma unroll
                for (int r = 0; r < 16; r++) acc[i][j][r] = 0.f;

        for (int st = 0; st < 9; st++) {
            const int d0 = st * DSTG;
            if (st < 8) {
                float4 zb[4], eb[4];
                #pragma unroll
                for (int rnd = 0; rnd < 4; rnd++) {
                    int flat = rnd * 256 + tid;
                    int row = flat >> 3, q = flat & 7;
                    zb[rnd] = *(const float4*)(z   + (size_t)(tok0  + row) * D_DIM + d0 + q * 4);
                    eb[rnd] = *(const float4*)(emb + (size_t)(code0 + row) * D_DIM + d0 + q * 4);
                }
                __syncthreads();
                #pragma unroll
                for (int rnd = 0; rnd < 4; rnd++) {
                    int flat = rnd * 256 + tid;
                    int row = flat >> 3, q = flat & 7;
                    wr4(zs_hi, zs_lo, row * LSTR + q * 4, zb[rnd]);
                    wr4(es_hi, es_lo, row * LSTR + q * 4, eb[rnd]);
                }
                __syncthreads();
                do_ksteps(2, zs_hi, zs_lo, es_hi, es_lo, acc, wt, wc, lane);
            } else {
                __syncthreads();
                // pad stage: fold ||e||^2: z_pad=1.0, e_pad=-e2/2 (hi+lo)
                bf16x4 zero4 = {0, 0, 0, 0};
                if (tid < BTOK) {
                    int row = tid;
                    bf16x4 one4 = {(short)0x3F80, 0, 0, 0};
                    *(bf16x4*)&zs_hi[row * LSTR + 0]  = one4;
                    *(bf16x4*)&zs_hi[row * LSTR + 4]  = zero4;
                    *(bf16x4*)&zs_hi[row * LSTR + 8]  = zero4;
                    *(bf16x4*)&zs_hi[row * LSTR + 12] = zero4;
                    *(bf16x4*)&zs_lo[row * LSTR + 0]  = zero4;
                    *(bf16x4*)&zs_lo[row * LSTR + 4]  = zero4;
                    *(bf16x4*)&zs_lo[row * LSTR + 8]  = zero4;
                    *(bf16x4*)&zs_lo[row * LSTR + 12] = zero4;
                } else {
                    int row = tid - BTOK;
                    short hh, ll;
                    split_bf16(-0.5f * e2np[code0 + row], hh, ll);
                    bf16x4 eh = {hh, 0, 0, 0}, el = {ll, 0, 0, 0};
                    *(bf16x4*)&es_hi[row * LSTR + 0]  = eh;
                    *(bf16x4*)&es_hi[row * LSTR + 4]  = zero4;
                    *(bf16x4*)&es_hi[row * LSTR + 8]  = zero4;
                    *(bf16x4*)&es_hi[row * LSTR + 12] = zero4;
                    *(bf16x4*)&es_lo[row * LSTR + 0]  = el;
                    *(bf16x4*)&es_lo[row * LSTR + 4]  = zero4;
                    *(bf16x4*)&es_lo[row * LSTR + 8]  = zero4;
                    *(bf16x4*)&es_lo[row * LSTR + 12] = zero4;
                }
                __syncthreads();
                do_ksteps(1, zs_hi, zs_lo, es_hi, es_lo, acc, wt, wc, lane);
            }
        }
        // top-2 insert; code ids ascend within each slot's insert sequence
        #pragma unroll
        for (int tt = 0; tt < 2; tt++) {
            #pragma unroll
            for (int tc = 0; tc < 2; tc++) {
                const int cbase = code0 + wc * 64 + tc * 32 + ((lane >> 5) << 2);
                #pragma unroll
                for (int r = 0; r < 16; r++) {
                    float a = acc[tc][tt][r];
                    int code = cbase + (r & 3) + ((r >> 2) << 3);
                    if (a > m1[tt]) { m2[tt] = m1[tt]; m1[tt] = a; k1[tt] = code; }
                    else if (a > m2[tt]) m2[tt] = a;
                }
            }
        }
    }

    // merge lane halves (same token, different code rows)
    #pragma unroll
    for (int tt = 0; tt < 2; tt++) {
        float o1 = __shfl_xor(m1[tt], 32);
        float o2 = __shfl_xor(m2[tt], 32);
        int   oi = __shfl_xor(k1[tt], 32);
        bool take = (o1 > m1[tt]) || (o1 == m1[tt] && oi < k1[tt]);
        float w1 = take ? o1 : m1[tt];
        int   wi = take ? oi : k1[tt];
        float ls = take ? m1[tt] : o1;
        m2[tt] = fmaxf(fmaxf(m2[tt], o2), ls);
        m1[tt] = w1; k1[tt] = wi;
    }
    __syncthreads();
    if (wc == 0 && lane < 32) {
        #pragma unroll
        for (int tt = 0; tt < 2; tt++) {
            int tl = wt * 64 + tt * 32 + lane;
            s1m[tl] = m1[tt]; s2m[tl] = m2[tt]; i1m[tl] = k1[tt];
        }
    }
    __syncthreads();
    if (wc == 1 && lane < 32) {
        #pragma unroll
        for (int tt = 0; tt < 2; tt++) {
            int tl = wt * 64 + tt * 32 + lane;
            float a1 = s1m[tl], a2 = s2m[tl]; int ai = i1m[tl];
            bool take = (a1 > m1[tt]) || (a1 == m1[tt] && ai < k1[tt]);
            float w1 = take ? a1 : m1[tt];
            int   wi = take ? ai : k1[tt];
            float ls = take ? m1[tt] : a1;
            float w2 = fmaxf(fmaxf(m2[tt], a2), ls);
            size_t t = (size_t)(tok0 + tl) * 2 + split;
            m1a[t] = w1; m2a[t] = w2; i1a[t] = wi;
        }
    }
}

// ---------------- merge splits, detect contested ----------------
__global__ __launch_bounds__(256) void merge_kernel(
    const float* __restrict__ m1a, const float* __restrict__ m2a,
    const int* __restrict__ i1a, float* __restrict__ m1f,
    int* __restrict__ idxf, int* __restrict__ clist, unsigned* __restrict__ ccount)
{
    int t = blockIdx.x * 256 + threadIdx.x;
    float a1 = m1a[t * 2], a2 = m2a[t * 2]; int ai = i1a[t * 2];
    float b1 = m1a[t * 2 + 1], b2 = m2a[t * 2 + 1]; int bi = i1a[t * 2 + 1];
    bool take = (b1 > a1) || (b1 == a1 && bi < ai);
    float w1 = take ? b1 : a1;
    int   wi = take ? bi : ai;
    float ls = take ? a1 : b1;
    float w2 = fmaxf(fmaxf(a2, b2), ls);
    idxf[t] = wi; m1f[t] = w1;
    if (w1 - w2 < CTAU_M) {
        unsigned p = atomicAdd(ccount, 1u);
        clist[p] = t;
    }
}

// ---------------- rescue: mfma candidate sweep + np-exact resolve ----------------
__global__ __launch_bounds__(256, 2) void rescue_kernel(
    const float* __restrict__ z, const float* __restrict__ emb,
    const float* __restrict__ e2np, const float* __restrict__ Cnp,
    const float* __restrict__ m1f, const unsigned* __restrict__ ccount,
    const int* __restrict__ clist, int* __restrict__ idxf)
{
    const unsigned count = *ccount;
    const unsigned base  = blockIdx.x * BTOK;
    if (base >= count) return;
    const int nt = min(BTOK, (int)(count - base));

    __shared__ __align__(16) short zs_hi[BTOK * LSTR], zs_lo[BTOK * LSTR];
    __shared__ __align__(16) short es_hi[CHUNK * LSTR], es_lo[CHUNK * LSTR];
    __shared__ int      tls[BTOK];
    __shared__ float    thr[BTOK];
    __shared__ unsigned ccnt[BTOK];
    __shared__ int      cand[BTOK][MAXCAND];

    const int tid  = threadIdx.x;
    const int lane = tid & 63;
    const int w    = tid >> 6;
    const int wt   = w & 1, wc = w >> 1;

    if (tid < BTOK) {
        int s = (tid < nt) ? tid : (nt - 1);
        int t = clist[base + s];
        tls[tid]  = t;
        thr[tid]  = (tid < nt) ? (m1f[t] - CAND_MM) : FLT_MAX;
        ccnt[tid] = 0u;
    }
    __syncthreads();

    float thrr[2];
    #pragma unroll
    for (int tt = 0; tt < 2; tt++) thrr[tt] = thr[wt * 64 + tt * 32 + (lane & 31)];

    for (int c = 0; c < K_CODES / CHUNK; c++) {
        const int code0 = c * CHUNK;
        f32x16 acc[2][2];
        #pragma unroll
        for (int i = 0; i < 2; i++)
            #pragma unroll
            for (int j = 0; j < 2; j++)
                #pragma unroll
                for (int r = 0; r < 16; r++) acc[i][j][r] = 0.f;

        for (int st = 0; st < 9; st++) {
            const int d0 = st * DSTG;
            if (st < 8) {
                float4 zb[4], eb[4];
                #pragma unroll
                for (int rnd = 0; rnd < 4; rnd++) {
                    int flat = rnd * 256 + tid;
                    int row = flat >> 3, q = flat & 7;
                    zb[rnd] = *(const float4*)(z   + (size_t)tls[row] * D_DIM + d0 + q * 4);
                    eb[rnd] = *(const float4*)(emb + (size_t)(code0 + row) * D_DIM + d0 + q * 4);
                }
                __syncthreads();
                #pragma unroll
                for (int rnd = 0; rnd < 4; rnd++) {
                    int flat = rnd * 256 + tid;
                    int row = flat >> 3, q = flat & 7;
                    wr4(zs_hi, zs_lo, row * LSTR + q * 4, zb[rnd]);
                    wr4(es_hi, es_lo, row * LSTR + q * 4, eb[rnd]);
                }
                __syncthreads();
                do_ksteps(2, zs_hi, zs_lo, es_hi, es_lo, acc, wt, wc, lane);
            } else {
                __syncthreads();
                bf16x4 zero4 = {0, 0, 0, 0};
                if (tid < BTOK) {
                    int row = tid;
                    bf16x4 one4 = {(short)0x3F80, 0, 0, 0};
                    *(bf16x4*)&zs_hi[row * LSTR + 0]  = one4;
                    *(bf16x4*)&zs_hi[row * LSTR + 4]  = zero4;
                    *(bf16x4*)&zs_hi[row * LSTR + 8]  = zero4;
                    *(bf16x4*)&zs_hi[row * LSTR + 12] = zero4;
                    *(bf16x4*)&zs_lo[row * LSTR + 0]  = zero4;
                    *(bf16x4*)&zs_lo[row * LSTR + 4]  = zero4;
                    *(bf16x4*)&zs_lo[row * LSTR + 8]  = zero4;
                    *(bf16x4*)&zs_lo[row * LSTR + 12] = zero4;
                } else {
                    int row = tid - BTOK;
                    short hh, ll;
                    split_bf16(-0.5f * e2np[code0 + row], hh, ll);
                    bf16x4 eh = {hh, 0, 0, 0}, el = {ll, 0, 0, 0};
                    *(bf16x4*)&es_hi[row * LSTR + 0]  = eh;
                    *(bf16x4*)&es_hi[row * LSTR + 4]  = zero4;
                    *(bf16x4*)&es_hi[row * LSTR + 8]  = zero4;
                    *(bf16x4*)&es_hi[row * LSTR + 12] = zero4;
                    *(bf16x4*)&es_lo[row * LSTR + 0]  = el;
                    *(bf16x4*)&es_lo[row * LSTR + 4]  = zero4;
                    *(bf16x4*)&es_lo[row * LSTR + 8]  = zero4;
                    *(bf16x4*)&es_lo[row * LSTR + 12] = zero4;
                }
                __syncthreads();
                do_ksteps(1, zs_hi, zs_lo, es_hi, es_lo, acc, wt, wc, lane);
            }
        }
        // collect candidates >= thr
        #pragma unroll
        for (int tt = 0; tt < 2; tt++) {
            const int tl = wt * 64 + tt * 32 + (lane & 31);
            #pragma unroll
            for (int tc = 0; tc < 2; tc++) {
                const int cbase = code0 + wc * 64 + tc * 32 + ((lane >> 5) << 2);
                #pragma unroll
                for (int r = 0; r < 16; r++) {
                    float a = acc[tc][tt][r];
                    if (a >= thrr[tt]) {
                        int code = cbase + (r & 3) + ((r >> 2) << 3);
                        unsigned p = atomicAdd(&ccnt[tl], 1u);
                        if (p < MAXCAND) cand[tl][p] = code;
                    }
                }
            }
        }
    }
    __syncthreads();

    // phase 2: np-exact d over candidates; first-index min == np.argmin
    for (int s = w * 32; s < w * 32 + 32; s++) {
        if (s >= nt) break;
        const int t = tls[s];
        const int n = (int)min(ccnt[s], (unsigned)MAXCAND);
        float bd = FLT_MAX; int bk = 0x7fffffff;
        if (lane < n) {
            const int k = cand[s][lane];
            float gdot = np_einsum256(z + (size_t)t * D_DIM, emb + (size_t)k * D_DIM);
            bd = np_dtilde(Cnp[t], e2np[k], gdot);
            bk = k;
        }
        #pragma unroll
        for (int off = 32; off >= 1; off >>= 1) {
            float od = __shfl_xor(bd, off);
            int   ok = __shfl_xor(bk, off);
            if (od < bd || (od == bd && ok < bk)) { bd = od; bk = ok; }
        }
        if (lane == 0 && n > 0) idxf[t] = bk;
    }
}

// ---------------- gather z_q, write out0, fp64 MSE sum ----------------
__global__ __launch_bounds__(256) void out_loss_kernel(
    const float* __restrict__ z, const float* __restrict__ emb,
    const int* __restrict__ idxf, float* __restrict__ out0,
    double* __restrict__ loss_sum)
{
    const int total4 = N_TOK * (D_DIM / 4);
    double lsum = 0.0;
    for (int p = blockIdx.x * 256 + threadIdx.x; p < total4; p += gridDim.x * 256) {
        const int n  = p >> 6;
        const int d4 = p & 63;
        const int k  = idxf[n];
        float4 zv = ((const float4*)z)[p];
        float4 ev = ((const float4*)(emb + (size_t)k * D_DIM))[d4];
        float dx = ev.x - zv.x, dy = ev.y - zv.y,
              dz = ev.z - zv.z, dw = ev.w - zv.w;
        float4 o;
        o.x = zv.x + dx; o.y = zv.y + dy; o.z = zv.z + dz; o.w = zv.w + dw;
        ((float4*)out0)[p] = o;
        lsum += (double)dx * dx + (double)dy * dy
              + (double)dz * dz + (double)dw * dw;
    }
    #pragma unroll
    for (int off = 32; off >= 1; off >>= 1) lsum += __shfl_xor(lsum, off);
    __shared__ double wsum[4];
    const int wv = threadIdx.x >> 6;
    if ((threadIdx.x & 63) == 0) wsum[wv] = lsum;
    __syncthreads();
    if (threadIdx.x == 0)
        atomicAdd(loss_sum, wsum[0] + wsum[1] + wsum[2] + wsum[3]);
}

__global__ __launch_bounds__(256) void finalize_kernel(
    const int* __restrict__ idxf, const double* __restrict__ loss_sum,
    float* __restrict__ out)
{
    const int t = blockIdx.x * 256 + threadIdx.x;
    if (t < N_TOK) out[8388611 + t] = (float)idxf[t];
    if (t == 0) {
        double mse = *loss_sum * (1.0 / 8388608.0);
        out[8388608] = (float)(1.25 * mse);
        out[8388609] = (float)(0.25 * mse);
        out[8388610] = (float)mse;
    }
}

extern "C" void kernel_launch(void* const* d_in, const int* in_sizes, int n_in,
                              void* d_out, int out_size, void* d_ws, size_t ws_size,
                              hipStream_t stream)
{
    const float* z   = (const float*)d_in[0];
    const float* emb = (const float*)d_in[1];
    float* out = (float*)d_out;
    char*  ws  = (char*)d_ws;

    double*   loss_sum = (double*)(ws + 0);
    unsigned* ccount   = (unsigned*)(ws + 8);
    float*    e2np     = (float*)(ws + 16);
    float*    Cnp      = (float*)(ws + 32784);
    float*    m1f      = (float*)(ws + 163856);
    int*      idxf     = (int*)(ws + 294928);
    int*      clist    = (int*)(ws + 426000);
    float*    m1a      = (float*)(ws + 557072);
    float*    m2a      = (float*)(ws + 819216);
    int*      i1a      = (int*)(ws + 1081360);

    prep_e_kernel<<<dim3(K_CODES / 256), dim3(256), 0, stream>>>(
        emb, e2np, ccount, loss_sum);
    prep_z_kernel<<<dim3(N_TOK / 256), dim3(256), 0, stream>>>(z, Cnp);
    bulk_kernel<<<dim3((N_TOK / BTOK) * NSPLIT), dim3(256), 0, stream>>>(
        z, emb, e2np, m1a, m2a, i1a);
    merge_kernel<<<dim3(N_TOK / 256), dim3(256), 0, stream>>>(
        m1a, m2a, i1a, m1f, idxf, clist, ccount);
    rescue_kernel<<<dim3(N_TOK / BTOK), dim3(256), 0, stream>>>(
        z, emb, e2np, Cnp, m1f, ccount, clist, idxf);
    out_loss_kernel<<<dim3(1024), dim3(256), 0, stream>>>(
        z, emb, idxf, out, loss_sum);
    finalize_kernel<<<dim3(N_TOK / 256), dim3(256), 0, stream>>>(
        idxf, loss_sum, out);
}

// Round 5
// 1122.225 us; speedup vs baseline: 4.1089x; 2.4051x over previous
//
#include <hip/hip_runtime.h>
#include <cfloat>

#define N_TOK   32768
#define K_CODES 8192
#define D_DIM   256
#define BTOK    128        // tokens per bulk block
#define CHUNK   128        // codes per chunk
#define NSPLIT  2          // code-range splits in bulk
#define SPLITK  (K_CODES / NSPLIT)
#define DSTG    32         // d per LDS stage
#define LSTR    36         // LDS row stride in shorts (bank-conflict pad)
#define CTAU_M  3.0e-5f    // contested if (m1-m2) < this (acc units; s-gap = 2x)
#define CAND_MM 2.4e-5f    // rescue candidate window (acc units; 4.8e-5 in s)
#define MAXCAND 16
#define RBTOK   32         // tokens per rescue block
#define NRS     8          // code splits in rescue
#define RSPLIT  (K_CODES / NRS)

typedef __attribute__((ext_vector_type(4)))  short bf16x4;
typedef __attribute__((ext_vector_type(8)))  short bf16x8;
typedef __attribute__((ext_vector_type(16))) float f32x16;

// ws layout (bytes):
//   0       double   loss_sum
//   8       unsigned ccount
//   16      float e2np[8192]
//   32784   float Cnp[32768]
//   163856  float m1f[32768]
//   294928  int   idxf[32768]
//   426000  int   clist[32768]
//   557072  float m1a[32768*2]
//   819216  float m2a[32768*2]
//   1081360 int   i1a[32768*2]
//   1343504 unsigned ccnt_g[32768]
//   1474576 int   cand_g[32768*16]   (2 MB) -> end 3571728

// ======== numpy bit-exact fp32 emulation (NO fma contraction) ========
__device__ __forceinline__ float np_sumsq256(const float* __restrict__ row) {
    #pragma clang fp contract(off)
    float blk[2];
    #pragma unroll
    for (int b = 0; b < 2; b++) {
        const float* x = row + b * 128;
        float r[8];
        #pragma unroll
        for (int j = 0; j < 8; j++) { float v = x[j]; r[j] = v * v; }
        for (int i = 8; i < 128; i += 8) {
            #pragma unroll
            for (int j = 0; j < 8; j++) { float v = x[i + j]; r[j] += v * v; }
        }
        blk[b] = ((r[0] + r[1]) + (r[2] + r[3])) + ((r[4] + r[5]) + (r[6] + r[7]));
    }
    return blk[0] + blk[1];
}

__device__ __forceinline__ float np_einsum256(const float* __restrict__ a,
                                              const float* __restrict__ b) {
    #pragma clang fp contract(off)
    float A0 = 0.f, A1 = 0.f, A2 = 0.f, A3 = 0.f;
    for (int m = 0; m < 256; m += 16) {
        A0 = a[m+ 0]*b[m+ 0] + (a[m+ 4]*b[m+ 4] + (a[m+ 8]*b[m+ 8] + (a[m+12]*b[m+12] + A0)));
        A1 = a[m+ 1]*b[m+ 1] + (a[m+ 5]*b[m+ 5] + (a[m+ 9]*b[m+ 9] + (a[m+13]*b[m+13] + A1)));
        A2 = a[m+ 2]*b[m+ 2] + (a[m+ 6]*b[m+ 6] + (a[m+10]*b[m+10] + (a[m+14]*b[m+14] + A2)));
        A3 = a[m+ 3]*b[m+ 3] + (a[m+ 7]*b[m+ 7] + (a[m+11]*b[m+11] + (a[m+15]*b[m+15] + A3)));
    }
    return (A0 + A1) + (A2 + A3);
}

__device__ __forceinline__ float np_dtilde(float Cn, float e2k, float g) {
    #pragma clang fp contract(off)
    float t = Cn + e2k;
    float d = t - 2.0f * g;
    return d;
}

// ======== bf16 split helpers ========
__device__ __forceinline__ unsigned short bf16_rne(float f) {
    unsigned u = __float_as_uint(f);
    unsigned r = u + 0x7fffu + ((u >> 16) & 1u);
    return (unsigned short)(r >> 16);
}
__device__ __forceinline__ float bf16_f(unsigned short h) {
    return __uint_as_float(((unsigned)h) << 16);
}
__device__ __forceinline__ void split_bf16(float f, short& hi, short& lo) {
    unsigned short h = bf16_rne(f);
    hi = (short)h;
    lo = (short)bf16_rne(f - bf16_f(h));
}

__device__ __forceinline__ bf16x8 rd8(const short* p) {
    bf16x8 v;
    *(bf16x4*)&v       = *(const bf16x4*)p;
    *((bf16x4*)&v + 1) = *(const bf16x4*)(p + 4);
    return v;
}
__device__ __forceinline__ void wr4(short* hi, short* lo, int idx, float4 v) {
    short h0, l0, h1, l1, h2, l2, h3, l3;
    split_bf16(v.x, h0, l0); split_bf16(v.y, h1, l1);
    split_bf16(v.z, h2, l2); split_bf16(v.w, h3, l3);
    bf16x4 vh = {h0, h1, h2, h3};
    bf16x4 vl = {l0, l1, l2, l3};
    *(bf16x4*)&hi[idx] = vh;
    *(bf16x4*)&lo[idx] = vl;
}

#define MFMA3(A, ah, al, bh, bl) \
    A = __builtin_amdgcn_mfma_f32_32x32x16_bf16(ah, bh, A, 0, 0, 0); \
    A = __builtin_amdgcn_mfma_f32_32x32x16_bf16(ah, bl, A, 0, 0, 0); \
    A = __builtin_amdgcn_mfma_f32_32x32x16_bf16(al, bh, A, 0, 0, 0);

// 12 mfma per kstep: acc[tc][tt] += e_tile(tc) x z_tile(tt), split 3-term
__device__ __forceinline__ void do_ksteps(
    int nks, const short* zs_hi, const short* zs_lo,
    const short* es_hi, const short* es_lo,
    f32x16 acc[2][2], int wt, int wc, int lane)
{
    const int half8 = ((lane >> 5) << 3);
    const int arow = (wc * 64 + (lane & 31)) * LSTR + half8;
    const int brow = (wt * 64 + (lane & 31)) * LSTR + half8;
    for (int ks = 0; ks < nks; ks++) {
        const int ko = ks * 16;
        bf16x8 a0h = rd8(&es_hi[arow + ko]);
        bf16x8 a0l = rd8(&es_lo[arow + ko]);
        bf16x8 a1h = rd8(&es_hi[arow + 32 * LSTR + ko]);
        bf16x8 a1l = rd8(&es_lo[arow + 32 * LSTR + ko]);
        bf16x8 b0h = rd8(&zs_hi[brow + ko]);
        bf16x8 b0l = rd8(&zs_lo[brow + ko]);
        bf16x8 b1h = rd8(&zs_hi[brow + 32 * LSTR + ko]);
        bf16x8 b1l = rd8(&zs_lo[brow + 32 * LSTR + ko]);
        MFMA3(acc[0][0], a0h, a0l, b0h, b0l);
        MFMA3(acc[0][1], a0h, a0l, b1h, b1l);
        MFMA3(acc[1][0], a1h, a1l, b0h, b0l);
        MFMA3(acc[1][1], a1h, a1l, b1h, b1l);
    }
}

// ---------------- prep kernels ----------------
__global__ __launch_bounds__(256) void prep_e_kernel(
    const float* __restrict__ emb, float* __restrict__ e2np,
    unsigned* __restrict__ ccount, double* __restrict__ loss_sum)
{
    int k = blockIdx.x * 256 + threadIdx.x;
    e2np[k] = np_sumsq256(emb + (size_t)k * D_DIM);
    if (k == 0) { *ccount = 0u; *loss_sum = 0.0; }
}

__global__ __launch_bounds__(256) void prep_z_kernel(
    const float* __restrict__ z, float* __restrict__ Cnp)
{
    int t = blockIdx.x * 256 + threadIdx.x;
    Cnp[t] = np_sumsq256(z + (size_t)t * D_DIM);
}

// ---------------- bulk mfma scan: 128 tok x 4096 codes per block ----------------
__global__ __launch_bounds__(256, 3) void bulk_kernel(
    const float* __restrict__ z, const float* __restrict__ emb,
    const float* __restrict__ e2np,
    float* __restrict__ m1a, float* __restrict__ m2a, int* __restrict__ i1a)
{
    __shared__ __align__(16) short zs_hi[BTOK * LSTR], zs_lo[BTOK * LSTR];
    __shared__ __align__(16) short es_hi[CHUNK * LSTR], es_lo[CHUNK * LSTR];
    __shared__ float s1m[BTOK], s2m[BTOK];
    __shared__ int   i1m[BTOK];

    const int tid  = threadIdx.x;
    const int lane = tid & 63;
    const int w    = tid >> 6;
    const int wt   = w & 1, wc = w >> 1;
    const int g     = blockIdx.x & 255;
    const int split = blockIdx.x >> 8;
    const int tok0  = g * BTOK;
    const int cs0   = split * SPLITK;

    float m1[2] = {-FLT_MAX, -FLT_MAX}, m2[2] = {-FLT_MAX, -FLT_MAX};
    int   k1[2] = {0x7fffffff, 0x7fffffff};

    for (int c = 0; c < SPLITK / CHUNK; c++) {
        const int code0 = cs0 + c * CHUNK;
        f32x16 acc[2][2];
        #pragma unroll
        for (int i = 0; i < 2; i++)
            #pragma unroll
            for (int j = 0; j < 2; j++)
                #pragma unroll
                for (int r = 0; r < 16; r++) acc[i][j][r] = 0.f;

        for (int st = 0; st < 9; st++) {
            const int d0 = st * DSTG;
            if (st < 8) {
                float4 zb[4], eb[4];
                #pragma unroll
                for (int rnd = 0; rnd < 4; rnd++) {
                    int flat = rnd * 256 + tid;
                    int row = flat >> 3, q = flat & 7;
                    zb[rnd] = *(const float4*)(z   + (size_t)(tok0  + row) * D_DIM + d0 + q * 4);
                    eb[rnd] = *(const float4*)(emb + (size_t)(code0 + row) * D_DIM + d0 + q * 4);
                }
                __syncthreads();
                #pragma unroll
                for (int rnd = 0; rnd < 4; rnd++) {
                    int flat = rnd * 256 + tid;
                    int row = flat >> 3, q = flat & 7;
                    wr4(zs_hi, zs_lo, row * LSTR + q * 4, zb[rnd]);
                    wr4(es_hi, es_lo, row * LSTR + q * 4, eb[rnd]);
                }
                __syncthreads();
                do_ksteps(2, zs_hi, zs_lo, es_hi, es_lo, acc, wt, wc, lane);
            } else {
                __syncthreads();
                // pad stage: fold ||e||^2: z_pad=1.0, e_pad=-e2/2 (hi+lo)
                bf16x4 zero4 = {0, 0, 0, 0};
                if (tid < BTOK) {
                    int row = tid;
                    bf16x4 one4 = {(short)0x3F80, 0, 0, 0};
                    *(bf16x4*)&zs_hi[row * LSTR + 0]  = one4;
                    *(bf16x4*)&zs_hi[row * LSTR + 4]  = zero4;
                    *(bf16x4*)&zs_hi[row * LSTR + 8]  = zero4;
                    *(bf16x4*)&zs_hi[row * LSTR + 12] = zero4;
                    *(bf16x4*)&zs_lo[row * LSTR + 0]  = zero4;
                    *(bf16x4*)&zs_lo[row * LSTR + 4]  = zero4;
                    *(bf16x4*)&zs_lo[row * LSTR + 8]  = zero4;
                    *(bf16x4*)&zs_lo[row * LSTR + 12] = zero4;
                } else {
                    int row = tid - BTOK;
                    short hh, ll;
                    split_bf16(-0.5f * e2np[code0 + row], hh, ll);
                    bf16x4 eh = {hh, 0, 0, 0}, el = {ll, 0, 0, 0};
                    *(bf16x4*)&es_hi[row * LSTR + 0]  = eh;
                    *(bf16x4*)&es_hi[row * LSTR + 4]  = zero4;
                    *(bf16x4*)&es_hi[row * LSTR + 8]  = zero4;
                    *(bf16x4*)&es_hi[row * LSTR + 12] = zero4;
                    *(bf16x4*)&es_lo[row * LSTR + 0]  = el;
                    *(bf16x4*)&es_lo[row * LSTR + 4]  = zero4;
                    *(bf16x4*)&es_lo[row * LSTR + 8]  = zero4;
                    *(bf16x4*)&es_lo[row * LSTR + 12] = zero4;
                }
                __syncthreads();
                do_ksteps(1, zs_hi, zs_lo, es_hi, es_lo, acc, wt, wc, lane);
            }
        }
        // top-2 insert
        #pragma unroll
        for (int tt = 0; tt < 2; tt++) {
            #pragma unroll
            for (int tc = 0; tc < 2; tc++) {
                const int cbase = code0 + wc * 64 + tc * 32 + ((lane >> 5) << 2);
                #pragma unroll
                for (int r = 0; r < 16; r++) {
                    float a = acc[tc][tt][r];
                    int code = cbase + (r & 3) + ((r >> 2) << 3);
                    if (a > m1[tt]) { m2[tt] = m1[tt]; m1[tt] = a; k1[tt] = code; }
                    else if (a > m2[tt]) m2[tt] = a;
                }
            }
        }
    }

    // merge lane halves (same token, different code rows)
    #pragma unroll
    for (int tt = 0; tt < 2; tt++) {
        float o1 = __shfl_xor(m1[tt], 32);
        float o2 = __shfl_xor(m2[tt], 32);
        int   oi = __shfl_xor(k1[tt], 32);
        bool take = (o1 > m1[tt]) || (o1 == m1[tt] && oi < k1[tt]);
        float w1 = take ? o1 : m1[tt];
        int   wi = take ? oi : k1[tt];
        float ls = take ? m1[tt] : o1;
        m2[tt] = fmaxf(fmaxf(m2[tt], o2), ls);
        m1[tt] = w1; k1[tt] = wi;
    }
    __syncthreads();
    if (wc == 0 && lane < 32) {
        #pragma unroll
        for (int tt = 0; tt < 2; tt++) {
            int tl = wt * 64 + tt * 32 + lane;
            s1m[tl] = m1[tt]; s2m[tl] = m2[tt]; i1m[tl] = k1[tt];
        }
    }
    __syncthreads();
    if (wc == 1 && lane < 32) {
        #pragma unroll
        for (int tt = 0; tt < 2; tt++) {
            int tl = wt * 64 + tt * 32 + lane;
            float a1 = s1m[tl], a2 = s2m[tl]; int ai = i1m[tl];
            bool take = (a1 > m1[tt]) || (a1 == m1[tt] && ai < k1[tt]);
            float w1 = take ? a1 : m1[tt];
            int   wi = take ? ai : k1[tt];
            float ls = take ? m1[tt] : a1;
            float w2 = fmaxf(fmaxf(m2[tt], a2), ls);
            size_t t = (size_t)(tok0 + tl) * 2 + split;
            m1a[t] = w1; m2a[t] = w2; i1a[t] = wi;
        }
    }
}

// ---------------- merge splits, detect contested, zero cand counters ----------------
__global__ __launch_bounds__(256) void merge_kernel(
    const float* __restrict__ m1a, const float* __restrict__ m2a,
    const int* __restrict__ i1a, float* __restrict__ m1f,
    int* __restrict__ idxf, int* __restrict__ clist,
    unsigned* __restrict__ ccount, unsigned* __restrict__ ccnt_g)
{
    int t = blockIdx.x * 256 + threadIdx.x;
    ccnt_g[t] = 0u;
    float a1 = m1a[t * 2], a2 = m2a[t * 2]; int ai = i1a[t * 2];
    float b1 = m1a[t * 2 + 1], b2 = m2a[t * 2 + 1]; int bi = i1a[t * 2 + 1];
    bool take = (b1 > a1) || (b1 == a1 && bi < ai);
    float w1 = take ? b1 : a1;
    int   wi = take ? bi : ai;
    float ls = take ? a1 : b1;
    float w2 = fmaxf(fmaxf(a2, b2), ls);
    idxf[t] = wi; m1f[t] = w1;
    if (w1 - w2 < CTAU_M) {
        unsigned p = atomicAdd(ccount, 1u);
        clist[p] = t;
    }
}

// ---------------- rescue: parallel mfma candidate sweep ----------------
// Grid (N_TOK/RBTOK, NRS): 32 tokens x 1024 codes per block; candidates appended
// to global per-token lists. acc recomputation is bit-identical to bulk's
// (same k-order, same MFMA3 sequence; mfma element value is column-independent).
__global__ __launch_bounds__(256, 2) void rescue_kernel(
    const float* __restrict__ z, const float* __restrict__ emb,
    const float* __restrict__ e2np, const float* __restrict__ m1f,
    const unsigned* __restrict__ ccount, const int* __restrict__ clist,
    unsigned* __restrict__ ccnt_g, int* __restrict__ cand_g)
{
    const unsigned count = *ccount;
    const unsigned base  = blockIdx.x * RBTOK;
    if (base >= count) return;
    const int nt = min(RBTOK, (int)(count - base));
    const int sp = blockIdx.y;

    __shared__ __align__(16) short zs_hi[RBTOK * LSTR], zs_lo[RBTOK * LSTR];
    __shared__ __align__(16) short es_hi[CHUNK * LSTR], es_lo[CHUNK * LSTR];
    __shared__ int   tls[RBTOK];
    __shared__ float thr[RBTOK];

    const int tid  = threadIdx.x;
    const int lane = tid & 63;
    const int w    = tid >> 6;

    if (tid < RBTOK) {
        int s = (tid < nt) ? tid : (nt - 1);
        int t = clist[base + s];
        tls[tid] = t;
        thr[tid] = (tid < nt) ? (m1f[t] - CAND_MM) : FLT_MAX;
    }
    __syncthreads();

    const float mythr = thr[lane & 31];
    const int   mytok = tls[lane & 31];
    const int half8 = ((lane >> 5) << 3);
    const int arow = (w * 32 + (lane & 31)) * LSTR + half8;   // codes
    const int brow = (lane & 31) * LSTR + half8;              // tokens

    for (int c = 0; c < RSPLIT / CHUNK; c++) {
        const int code0 = sp * RSPLIT + c * CHUNK;
        f32x16 acc;
        #pragma unroll
        for (int r = 0; r < 16; r++) acc[r] = 0.f;

        for (int st = 0; st < 9; st++) {
            const int d0 = st * DSTG;
            if (st < 8) {
                // z: 32 rows x 8 float4 = 256 loads (1/thread); emb: 128 rows = 4/thread
                int zrow = tid >> 3, zq = tid & 7;
                float4 zb = *(const float4*)(z + (size_t)tls[zrow] * D_DIM + d0 + zq * 4);
                float4 eb[4];
                #pragma unroll
                for (int rnd = 0; rnd < 4; rnd++) {
                    int flat = rnd * 256 + tid;
                    int row = flat >> 3, q = flat & 7;
                    eb[rnd] = *(const float4*)(emb + (size_t)(code0 + row) * D_DIM + d0 + q * 4);
                }
                __syncthreads();
                wr4(zs_hi, zs_lo, zrow * LSTR + zq * 4, zb);
                #pragma unroll
                for (int rnd = 0; rnd < 4; rnd++) {
                    int flat = rnd * 256 + tid;
                    int row = flat >> 3, q = flat & 7;
                    wr4(es_hi, es_lo, row * LSTR + q * 4, eb[rnd]);
                }
                __syncthreads();
                #pragma unroll
                for (int ks = 0; ks < 2; ks++) {
                    const int ko = ks * 16;
                    bf16x8 ah = rd8(&es_hi[arow + ko]);
                    bf16x8 al = rd8(&es_lo[arow + ko]);
                    bf16x8 bh = rd8(&zs_hi[brow + ko]);
                    bf16x8 bl = rd8(&zs_lo[brow + ko]);
                    MFMA3(acc, ah, al, bh, bl);
                }
            } else {
                __syncthreads();
                bf16x4 zero4 = {0, 0, 0, 0};
                if (tid < RBTOK) {
                    int row = tid;
                    bf16x4 one4 = {(short)0x3F80, 0, 0, 0};
                    *(bf16x4*)&zs_hi[row * LSTR + 0]  = one4;
                    *(bf16x4*)&zs_hi[row * LSTR + 4]  = zero4;
                    *(bf16x4*)&zs_hi[row * LSTR + 8]  = zero4;
                    *(bf16x4*)&zs_hi[row * LSTR + 12] = zero4;
                    *(bf16x4*)&zs_lo[row * LSTR + 0]  = zero4;
                    *(bf16x4*)&zs_lo[row * LSTR + 4]  = zero4;
                    *(bf16x4*)&zs_lo[row * LSTR + 8]  = zero4;
                    *(bf16x4*)&zs_lo[row * LSTR + 12] = zero4;
                } else if (tid >= 128) {
                    int row = tid - 128;
                    short hh, ll;
                    split_bf16(-0.5f * e2np[code0 + row], hh, ll);
                    bf16x4 eh = {hh, 0, 0, 0}, el = {ll, 0, 0, 0};
                    *(bf16x4*)&es_hi[row * LSTR + 0]  = eh;
                    *(bf16x4*)&es_hi[row * LSTR + 4]  = zero4;
                    *(bf16x4*)&es_hi[row * LSTR + 8]  = zero4;
                    *(bf16x4*)&es_hi[row * LSTR + 12] = zero4;
                    *(bf16x4*)&es_lo[row * LSTR + 0]  = el;
                    *(bf16x4*)&es_lo[row * LSTR + 4]  = zero4;
                    *(bf16x4*)&es_lo[row * LSTR + 8]  = zero4;
                    *(bf16x4*)&es_lo[row * LSTR + 12] = zero4;
                }
                __syncthreads();
                bf16x8 ah = rd8(&es_hi[arow]);
                bf16x8 al = rd8(&es_lo[arow]);
                bf16x8 bh = rd8(&zs_hi[brow]);
                bf16x8 bl = rd8(&zs_lo[brow]);
                MFMA3(acc, ah, al, bh, bl);
            }
        }
        // collect candidates
        #pragma unroll
        for (int r = 0; r < 16; r++) {
            float a = acc[r];
            if (a >= mythr) {
                int code = code0 + w * 32 + (r & 3) + ((lane >> 5) << 2) + ((r >> 2) << 3);
                unsigned p = atomicAdd(&ccnt_g[mytok], 1u);
                if (p < MAXCAND) cand_g[(size_t)mytok * MAXCAND + p] = code;
            }
        }
    }
}

// ---------------- resolve: np-exact d over candidates, first-index min ----------------
__global__ __launch_bounds__(256) void resolve_kernel(
    const float* __restrict__ z, const float* __restrict__ emb,
    const float* __restrict__ e2np, const float* __restrict__ Cnp,
    const unsigned* __restrict__ ccount, const int* __restrict__ clist,
    const unsigned* __restrict__ ccnt_g, const int* __restrict__ cand_g,
    int* __restrict__ idxf)
{
    const unsigned count = *ccount;
    const int lane = threadIdx.x & 63;
    const int w    = threadIdx.x >> 6;
    for (unsigned c = blockIdx.x * 4 + w; c < count; c += gridDim.x * 4) {
        const int t = clist[c];
        const int n = (int)min(ccnt_g[t], (unsigned)MAXCAND);
        float bd = FLT_MAX; int bk = 0x7fffffff;
        if (lane < n) {
            const int k = cand_g[(size_t)t * MAXCAND + lane];
            float g = np_einsum256(z + (size_t)t * D_DIM, emb + (size_t)k * D_DIM);
            bd = np_dtilde(Cnp[t], e2np[k], g);
            bk = k;
        }
        #pragma unroll
        for (int off = 32; off >= 1; off >>= 1) {
            float od = __shfl_xor(bd, off);
            int   ok = __shfl_xor(bk, off);
            if (od < bd || (od == bd && ok < bk)) { bd = od; bk = ok; }
        }
        if (lane == 0 && n > 0) idxf[t] = bk;
    }
}

// ---------------- gather z_q, write out0, fp64 MSE sum ----------------
__global__ __launch_bounds__(256) void out_loss_kernel(
    const float* __restrict__ z, const float* __restrict__ emb,
    const int* __restrict__ idxf, float* __restrict__ out0,
    double* __restrict__ loss_sum)
{
    const int total4 = N_TOK * (D_DIM / 4);
    double lsum = 0.0;
    for (int p = blockIdx.x * 256 + threadIdx.x; p < total4; p += gridDim.x * 256) {
        const int n  = p >> 6;
        const int d4 = p & 63;
        const int k  = idxf[n];
        float4 zv = ((const float4*)z)[p];
        float4 ev = ((const float4*)(emb + (size_t)k * D_DIM))[d4];
        float dx = ev.x - zv.x, dy = ev.y - zv.y,
              dz = ev.z - zv.z, dw = ev.w - zv.w;
        float4 o;
        o.x = zv.x + dx; o.y = zv.y + dy; o.z = zv.z + dz; o.w = zv.w + dw;
        ((float4*)out0)[p] = o;
        lsum += (double)dx * dx + (double)dy * dy
              + (double)dz * dz + (double)dw * dw;
    }
    #pragma unroll
    for (int off = 32; off >= 1; off >>= 1) lsum += __shfl_xor(lsum, off);
    __shared__ double wsum[4];
    const int wv = threadIdx.x >> 6;
    if ((threadIdx.x & 63) == 0) wsum[wv] = lsum;
    __syncthreads();
    if (threadIdx.x == 0)
        atomicAdd(loss_sum, wsum[0] + wsum[1] + wsum[2] + wsum[3]);
}

__global__ __launch_bounds__(256) void finalize_kernel(
    const int* __restrict__ idxf, const double* __restrict__ loss_sum,
    float* __restrict__ out)
{
    const int t = blockIdx.x * 256 + threadIdx.x;
    if (t < N_TOK) out[8388611 + t] = (float)idxf[t];
    if (t == 0) {
        double mse = *loss_sum * (1.0 / 8388608.0);
        out[8388608] = (float)(1.25 * mse);
        out[8388609] = (float)(0.25 * mse);
        out[8388610] = (float)mse;
    }
}

extern "C" void kernel_launch(void* const* d_in, const int* in_sizes, int n_in,
                              void* d_out, int out_size, void* d_ws, size_t ws_size,
                              hipStream_t stream)
{
    const float* z   = (const float*)d_in[0];
    const float* emb = (const float*)d_in[1];
    float* out = (float*)d_out;
    char*  ws  = (char*)d_ws;

    double*   loss_sum = (double*)(ws + 0);
    unsigned* ccount   = (unsigned*)(ws + 8);
    float*    e2np     = (float*)(ws + 16);
    float*    Cnp      = (float*)(ws + 32784);
    float*    m1f      = (float*)(ws + 163856);
    int*      idxf     = (int*)(ws + 294928);
    int*      clist    = (int*)(ws + 426000);
    float*    m1a      = (float*)(ws + 557072);
    float*    m2a      = (float*)(ws + 819216);
    int*      i1a      = (int*)(ws + 1081360);
    unsigned* ccnt_g   = (unsigned*)(ws + 1343504);
    int*      cand_g   = (int*)(ws + 1474576);

    prep_e_kernel<<<dim3(K_CODES / 256), dim3(256), 0, stream>>>(
        emb, e2np, ccount, loss_sum);
    prep_z_kernel<<<dim3(N_TOK / 256), dim3(256), 0, stream>>>(z, Cnp);
    bulk_kernel<<<dim3((N_TOK / BTOK) * NSPLIT), dim3(256), 0, stream>>>(
        z, emb, e2np, m1a, m2a, i1a);
    merge_kernel<<<dim3(N_TOK / 256), dim3(256), 0, stream>>>(
        m1a, m2a, i1a, m1f, idxf, clist, ccount, ccnt_g);
    rescue_kernel<<<dim3(N_TOK / RBTOK, NRS), dim3(256), 0, stream>>>(
        z, emb, e2np, m1f, ccount, clist, ccnt_g, cand_g);
    resolve_kernel<<<dim3(128), dim3(256), 0, stream>>>(
        z, emb, e2np, Cnp, ccount, clist, ccnt_g, cand_g, idxf);
    out_loss_kernel<<<dim3(1024), dim3(256), 0, stream>>>(
        z, emb, idxf, out, loss_sum);
    finalize_kernel<<<dim3(N_TOK / 256), dim3(256), 0, stream>>>(
        idxf, loss_sum, out);
}

// Round 8
// 904.637 us; speedup vs baseline: 5.0972x; 1.2405x over previous
//
#include <hip/hip_runtime.h>
#include <cfloat>

#define N_TOK   32768
#define K_CODES 8192
#define D_DIM   256
#define BTOK    128        // tokens per bulk block
#define CHUNK   128        // codes per chunk
#define NSPLIT  4          // code-range splits in bulk
#define SPLITK  (K_CODES / NSPLIT)
#define CTAU_M  3.0e-5f    // contested if (m1-m2) < this (acc units)
#define CAND_MM 2.4e-5f    // rescue candidate window (acc units)
#define MAXCAND 16
#define RBTOK   32         // tokens per rescue block
#define NRS     8          // code splits in rescue
#define RSPLIT  (K_CODES / NRS)

typedef __attribute__((ext_vector_type(4)))  short bf16x4;
typedef __attribute__((ext_vector_type(8)))  short bf16x8;
typedef __attribute__((ext_vector_type(16))) float f32x16;

// ws layout (bytes) — 720,912 B total (5x under known-good 3.57 MB):
//   0      double loss_sum ; 8 uint ccount (+pad)
//   16     float e2np[8192]
//   32784  float e2h[8192]      0.5*e2np
//   65552  float Cnp[32768]
//   196624 float m1f[32768]
//   327696 int   idxf[32768]
//   458768 int   clist[32768]
//   589840 uint  ccnt_g[32768]   -> end 720912
//
// d_out scratch (33,685,516 B buffer; fully rewritten by out_loss/finalize after
// all scratch reads complete — stream-ordered):
//   0        short ehi[8192*256]    (4,194,304)
//   4194304  short elo[8192*256]    (4,194,304)
//   8388608  short zhi[32768*256]   (16,777,216)
//   25165824 float m1a[32768*4]     (524,288)
//   25690112 float m2a[32768*4]     (524,288)
//   26214400 int   i1a[32768*4]     (524,288)
//   26738688 int   cand_g[32768*16] (2,097,152) -> end 28,835,840 < 33,685,516

// ======== numpy bit-exact fp32 emulation (NO fma contraction) ========
__device__ __forceinline__ float np_sumsq256(const float* __restrict__ row) {
    #pragma clang fp contract(off)
    float blk[2];
    #pragma unroll
    for (int b = 0; b < 2; b++) {
        const float* x = row + b * 128;
        float r[8];
        #pragma unroll
        for (int j = 0; j < 8; j++) { float v = x[j]; r[j] = v * v; }
        for (int i = 8; i < 128; i += 8) {
            #pragma unroll
            for (int j = 0; j < 8; j++) { float v = x[i + j]; r[j] += v * v; }
        }
        blk[b] = ((r[0] + r[1]) + (r[2] + r[3])) + ((r[4] + r[5]) + (r[6] + r[7]));
    }
    return blk[0] + blk[1];
}

__device__ __forceinline__ float np_einsum256(const float* __restrict__ a,
                                              const float* __restrict__ b) {
    #pragma clang fp contract(off)
    float A0 = 0.f, A1 = 0.f, A2 = 0.f, A3 = 0.f;
    for (int m = 0; m < 256; m += 16) {
        A0 = a[m+ 0]*b[m+ 0] + (a[m+ 4]*b[m+ 4] + (a[m+ 8]*b[m+ 8] + (a[m+12]*b[m+12] + A0)));
        A1 = a[m+ 1]*b[m+ 1] + (a[m+ 5]*b[m+ 5] + (a[m+ 9]*b[m+ 9] + (a[m+13]*b[m+13] + A1)));
        A2 = a[m+ 2]*b[m+ 2] + (a[m+ 6]*b[m+ 6] + (a[m+10]*b[m+10] + (a[m+14]*b[m+14] + A2)));
        A3 = a[m+ 3]*b[m+ 3] + (a[m+ 7]*b[m+ 7] + (a[m+11]*b[m+11] + (a[m+15]*b[m+15] + A3)));
    }
    return (A0 + A1) + (A2 + A3);
}

__device__ __forceinline__ float np_dtilde(float Cn, float e2k, float g) {
    #pragma clang fp contract(off)
    float t = Cn + e2k;
    float d = t - 2.0f * g;
    return d;
}

// ======== bf16 split helpers ========
__device__ __forceinline__ unsigned short bf16_rne(float f) {
    unsigned u = __float_as_uint(f);
    unsigned r = u + 0x7fffu + ((u >> 16) & 1u);
    return (unsigned short)(r >> 16);
}
__device__ __forceinline__ void split_bf16(float f, short& hi, short& lo) {
    unsigned short h = bf16_rne(f);
    hi = (short)h;
    float hf = __uint_as_float(((unsigned)h) << 16);
    lo = (short)bf16_rne(f - hf);
}
// lo granule from stored hi granule + fp32 source (bit-identical to split_bf16)
__device__ __forceinline__ bf16x8 lo8(bf16x8 h, float4 a, float4 b) {
    float f[8] = {a.x, a.y, a.z, a.w, b.x, b.y, b.z, b.w};
    bf16x8 r;
    #pragma unroll
    for (int i = 0; i < 8; i++) {
        float hf = __uint_as_float(((unsigned)(unsigned short)h[i]) << 16);
        r[i] = (short)bf16_rne(f[i] - hf);
    }
    return r;
}

#define MFMA3(A, ah, al, bh, bl) \
    A = __builtin_amdgcn_mfma_f32_32x32x16_bf16(ah, bh, A, 0, 0, 0); \
    A = __builtin_amdgcn_mfma_f32_32x32x16_bf16(ah, bl, A, 0, 0, 0); \
    A = __builtin_amdgcn_mfma_f32_32x32x16_bf16(al, bh, A, 0, 0, 0);

// ---------------- prep kernels ----------------
__global__ __launch_bounds__(256) void prep_e_kernel(
    const float* __restrict__ emb, float* __restrict__ e2np,
    float* __restrict__ e2h, unsigned* __restrict__ ccount,
    double* __restrict__ loss_sum)
{
    int k = blockIdx.x * 256 + threadIdx.x;
    float v = np_sumsq256(emb + (size_t)k * D_DIM);
    e2np[k] = v;
    e2h[k]  = 0.5f * v;
    if (k == 0) { *ccount = 0u; *loss_sum = 0.0; }
}

__global__ __launch_bounds__(256) void prep_z_kernel(
    const float* __restrict__ z, float* __restrict__ Cnp)
{
    int t = blockIdx.x * 256 + threadIdx.x;
    Cnp[t] = np_sumsq256(z + (size_t)t * D_DIM);
}

// ---------------- one-time conversions into d_out scratch ----------------
__global__ __launch_bounds__(256) void cvt_e_kernel(
    const float* __restrict__ src, short* __restrict__ hi, short* __restrict__ lo)
{
    size_t p = ((size_t)blockIdx.x * 256 + threadIdx.x) * 8;
    float4 v0 = *(const float4*)(src + p);
    float4 v1 = *(const float4*)(src + p + 4);
    short h[8], l[8];
    split_bf16(v0.x, h[0], l[0]); split_bf16(v0.y, h[1], l[1]);
    split_bf16(v0.z, h[2], l[2]); split_bf16(v0.w, h[3], l[3]);
    split_bf16(v1.x, h[4], l[4]); split_bf16(v1.y, h[5], l[5]);
    split_bf16(v1.z, h[6], l[6]); split_bf16(v1.w, h[7], l[7]);
    bf16x8 vh = {h[0],h[1],h[2],h[3],h[4],h[5],h[6],h[7]};
    bf16x8 vl = {l[0],l[1],l[2],l[3],l[4],l[5],l[6],l[7]};
    *(bf16x8*)(hi + p) = vh;
    *(bf16x8*)(lo + p) = vl;
}

__global__ __launch_bounds__(256) void cvt_zhi_kernel(
    const float* __restrict__ src, short* __restrict__ hi)
{
    size_t p = ((size_t)blockIdx.x * 256 + threadIdx.x) * 8;
    float4 v0 = *(const float4*)(src + p);
    float4 v1 = *(const float4*)(src + p + 4);
    bf16x8 vh = {(short)bf16_rne(v0.x), (short)bf16_rne(v0.y),
                 (short)bf16_rne(v0.z), (short)bf16_rne(v0.w),
                 (short)bf16_rne(v1.x), (short)bf16_rne(v1.y),
                 (short)bf16_rne(v1.z), (short)bf16_rne(v1.w)};
    *(bf16x8*)(hi + p) = vh;
}

// LDS short-offsets (bulk): ESH=0 ESL=4096 ZSH=8192 ZSL=12288; +1024 = +32 rows
#define B_ESH 0
#define B_ESL 4096
#define B_ZSH 8192
#define B_ZSL 12288
#define TILE1 1024

// ---------------- bulk mfma scan: 128 tok x 2048 codes per block ----------------
__global__ __launch_bounds__(256, 3) void bulk_kernel(
    const float* __restrict__ zf, const short* __restrict__ zhi,
    const short* __restrict__ ehi, const short* __restrict__ elo,
    const float* __restrict__ e2h,
    float* __restrict__ m1a, float* __restrict__ m2a, int* __restrict__ i1a)
{
    __shared__ __align__(16) short smem[16384];   // 32 KB
    __shared__ float e2s[CHUNK];
    __shared__ float s1m[BTOK], s2m[BTOK];
    __shared__ int   i1m[BTOK];

    const int tid  = threadIdx.x;
    const int lane = tid & 63;
    const int w    = tid >> 6;
    const int wt   = w & 1, wc = w >> 1;
    const int g     = blockIdx.x & 255;
    const int split = blockIdx.x >> 8;
    const int tok0  = g * BTOK;
    const int cs0   = split * SPLITK;

    // staging slots: two (row, quarter) granules per array
    const int r0 = tid >> 2, q0 = tid & 3;
    const int r1 = r0 + 64;
    const int so0 = r0 * 32 + ((q0 ^ ((r0 >> 1) & 3)) << 3);
    const int so1 = r1 * 32 + ((q0 ^ ((r1 >> 1) & 3)) << 3);

    // mfma read addressing (shorts), XOR-swizzled granules
    const int l31 = lane & 31, hh = lane >> 5;
    const int swz = (l31 >> 1) & 3;
    const int arow = (wc * 64 + l31) * 32;
    const int brow = (wt * 64 + l31) * 32;
    const int a0 = arow + ((hh ^ swz) << 3);
    const int a1 = arow + (((2 + hh) ^ swz) << 3);
    const int b0 = brow + ((hh ^ swz) << 3);
    const int b1 = brow + (((2 + hh) ^ swz) << 3);

    float m1[2] = {-FLT_MAX, -FLT_MAX}, m2[2] = {-FLT_MAX, -FLT_MAX};
    int   k1[2] = {0x7fffffff, 0x7fffffff};

    for (int c = 0; c < SPLITK / CHUNK; c++) {
        const int code0 = cs0 + c * CHUNK;
        const float e2v = (tid < CHUNK) ? e2h[code0 + tid] : 0.f;
        f32x16 acc[2][2];
        #pragma unroll
        for (int i = 0; i < 2; i++)
            #pragma unroll
            for (int j = 0; j < 2; j++)
                #pragma unroll
                for (int r = 0; r < 16; r++) acc[i][j][r] = 0.f;

        for (int st = 0; st < 8; st++) {
            const int d0 = st * 32;
            const size_t ei0 = ((size_t)(code0 + r0) << 8) + d0 + (q0 << 3);
            const size_t ei1 = ((size_t)(code0 + r1) << 8) + d0 + (q0 << 3);
            const size_t zi0 = ((size_t)(tok0 + r0) << 8) + d0 + (q0 << 3);
            const size_t zi1 = ((size_t)(tok0 + r1) << 8) + d0 + (q0 << 3);
            bf16x8 eh0 = *(const bf16x8*)(ehi + ei0);
            bf16x8 el0 = *(const bf16x8*)(elo + ei0);
            bf16x8 eh1 = *(const bf16x8*)(ehi + ei1);
            bf16x8 el1 = *(const bf16x8*)(elo + ei1);
            bf16x8 zh0 = *(const bf16x8*)(zhi + zi0);
            bf16x8 zh1 = *(const bf16x8*)(zhi + zi1);
            float4 zf0a = *(const float4*)(zf + zi0);
            float4 zf0b = *(const float4*)(zf + zi0 + 4);
            float4 zf1a = *(const float4*)(zf + zi1);
            float4 zf1b = *(const float4*)(zf + zi1 + 4);
            bf16x8 zl0 = lo8(zh0, zf0a, zf0b);
            bf16x8 zl1 = lo8(zh1, zf1a, zf1b);
            __syncthreads();   // prior-stage readers (incl. epilogue e2s reads) done
            *(bf16x8*)(smem + B_ESH + so0) = eh0;
            *(bf16x8*)(smem + B_ESL + so0) = el0;
            *(bf16x8*)(smem + B_ESH + so1) = eh1;
            *(bf16x8*)(smem + B_ESL + so1) = el1;
            *(bf16x8*)(smem + B_ZSH + so0) = zh0;
            *(bf16x8*)(smem + B_ZSL + so0) = zl0;
            *(bf16x8*)(smem + B_ZSH + so1) = zh1;
            *(bf16x8*)(smem + B_ZSL + so1) = zl1;
            if (st == 0 && tid < CHUNK) e2s[tid] = e2v;
            __syncthreads();
            {   // kstep 0
                bf16x8 a0h = *(const bf16x8*)(smem + B_ESH + a0);
                bf16x8 a0l = *(const bf16x8*)(smem + B_ESL + a0);
                bf16x8 a1h = *(const bf16x8*)(smem + B_ESH + TILE1 + a0);
                bf16x8 a1l = *(const bf16x8*)(smem + B_ESL + TILE1 + a0);
                bf16x8 b0h = *(const bf16x8*)(smem + B_ZSH + b0);
                bf16x8 b0l = *(const bf16x8*)(smem + B_ZSL + b0);
                bf16x8 b1h = *(const bf16x8*)(smem + B_ZSH + TILE1 + b0);
                bf16x8 b1l = *(const bf16x8*)(smem + B_ZSL + TILE1 + b0);
                MFMA3(acc[0][0], a0h, a0l, b0h, b0l);
                MFMA3(acc[0][1], a0h, a0l, b1h, b1l);
                MFMA3(acc[1][0], a1h, a1l, b0h, b0l);
                MFMA3(acc[1][1], a1h, a1l, b1h, b1l);
            }
            {   // kstep 1
                bf16x8 a0h = *(const bf16x8*)(smem + B_ESH + a1);
                bf16x8 a0l = *(const bf16x8*)(smem + B_ESL + a1);
                bf16x8 a1h = *(const bf16x8*)(smem + B_ESH + TILE1 + a1);
                bf16x8 a1l = *(const bf16x8*)(smem + B_ESL + TILE1 + a1);
                bf16x8 b0h = *(const bf16x8*)(smem + B_ZSH + b1);
                bf16x8 b0l = *(const bf16x8*)(smem + B_ZSL + b1);
                bf16x8 b1h = *(const bf16x8*)(smem + B_ZSH + TILE1 + b1);
                bf16x8 b1l = *(const bf16x8*)(smem + B_ZSL + TILE1 + b1);
                MFMA3(acc[0][0], a0h, a0l, b0h, b0l);
                MFMA3(acc[0][1], a0h, a0l, b1h, b1l);
                MFMA3(acc[1][0], a1h, a1l, b0h, b0l);
                MFMA3(acc[1][1], a1h, a1l, b1h, b1l);
            }
        }
        // epilogue: a = acc - e2/2 (broadcast LDS reads), top-2 insert
        #pragma unroll
        for (int tc = 0; tc < 2; tc++) {
            float ev[16];
            #pragma unroll
            for (int r = 0; r < 16; r++)
                ev[r] = e2s[wc * 64 + tc * 32 + hh * 4 + (r & 3) + ((r >> 2) << 3)];
            #pragma unroll
            for (int tt = 0; tt < 2; tt++) {
                #pragma unroll
                for (int r = 0; r < 16; r++) {
                    float a = acc[tc][tt][r] - ev[r];
                    int code = code0 + wc * 64 + tc * 32 + hh * 4 + (r & 3) + ((r >> 2) << 3);
                    if (a > m1[tt]) { m2[tt] = m1[tt]; m1[tt] = a; k1[tt] = code; }
                    else if (a > m2[tt]) m2[tt] = a;
                }
            }
        }
    }

    // merge lane halves (same token columns, different code rows)
    #pragma unroll
    for (int tt = 0; tt < 2; tt++) {
        float o1 = __shfl_xor(m1[tt], 32);
        float o2 = __shfl_xor(m2[tt], 32);
        int   oi = __shfl_xor(k1[tt], 32);
        bool take = (o1 > m1[tt]) || (o1 == m1[tt] && oi < k1[tt]);
        float w1 = take ? o1 : m1[tt];
        int   wi = take ? oi : k1[tt];
        float ls = take ? m1[tt] : o1;
        m2[tt] = fmaxf(fmaxf(m2[tt], o2), ls);
        m1[tt] = w1; k1[tt] = wi;
    }
    __syncthreads();
    if (wc == 0 && lane < 32) {
        #pragma unroll
        for (int tt = 0; tt < 2; tt++) {
            int tl = wt * 64 + tt * 32 + lane;
            s1m[tl] = m1[tt]; s2m[tl] = m2[tt]; i1m[tl] = k1[tt];
        }
    }
    __syncthreads();
    if (wc == 1 && lane < 32) {
        #pragma unroll
        for (int tt = 0; tt < 2; tt++) {
            int tl = wt * 64 + tt * 32 + lane;
            float a1 = s1m[tl], a2 = s2m[tl]; int ai = i1m[tl];
            bool take = (a1 > m1[tt]) || (a1 == m1[tt] && ai < k1[tt]);
            float w1 = take ? a1 : m1[tt];
            int   wi = take ? ai : k1[tt];
            float ls = take ? m1[tt] : a1;
            float w2 = fmaxf(fmaxf(m2[tt], a2), ls);
            size_t t = (size_t)(tok0 + tl) * NSPLIT + split;
            m1a[t] = w1; m2a[t] = w2; i1a[t] = wi;
        }
    }
}

// ---------------- merge splits, detect contested, zero cand counters ----------------
__global__ __launch_bounds__(256) void merge_kernel(
    const float* __restrict__ m1a, const float* __restrict__ m2a,
    const int* __restrict__ i1a, float* __restrict__ m1f,
    int* __restrict__ idxf, int* __restrict__ clist,
    unsigned* __restrict__ ccount, unsigned* __restrict__ ccnt_g)
{
    int t = blockIdx.x * 256 + threadIdx.x;
    ccnt_g[t] = 0u;
    float w1 = m1a[t * NSPLIT], w2 = m2a[t * NSPLIT];
    int   wi = i1a[t * NSPLIT];
    #pragma unroll
    for (int s = 1; s < NSPLIT; s++) {
        float a1 = m1a[t * NSPLIT + s], a2 = m2a[t * NSPLIT + s];
        int   ai = i1a[t * NSPLIT + s];
        bool take = (a1 > w1) || (a1 == w1 && ai < wi);
        float n1 = take ? a1 : w1;
        int   ni = take ? ai : wi;
        float ls = take ? w1 : a1;
        w2 = fmaxf(fmaxf(w2, a2), ls);
        w1 = n1; wi = ni;
    }
    idxf[t] = wi; m1f[t] = w1;
    if (w1 - w2 < CTAU_M) {
        unsigned p = atomicAdd(ccount, 1u);
        clist[p] = t;
    }
}

// LDS short-offsets (rescue): ESH=0 ESL=4096 ZSH=8192 ZSL=9216
#define R_ESH 0
#define R_ESL 4096
#define R_ZSH 8192
#define R_ZSL 9216

// ---------------- rescue: parallel mfma candidate sweep (32 tok x 1024 codes) ----------------
__global__ __launch_bounds__(256) void rescue_kernel(
    const float* __restrict__ zf, const short* __restrict__ zhi,
    const short* __restrict__ ehi, const short* __restrict__ elo,
    const float* __restrict__ e2h, const float* __restrict__ m1f,
    const unsigned* __restrict__ ccount, const int* __restrict__ clist,
    unsigned* __restrict__ ccnt_g, int* __restrict__ cand_g)
{
    const unsigned count = *ccount;
    const unsigned base  = blockIdx.x * RBTOK;
    if (base >= count) return;
    const int nt = min(RBTOK, (int)(count - base));
    const int sp = blockIdx.y;

    __shared__ __align__(16) short rsm[10240];   // 20 KB
    __shared__ int   tls[RBTOK];
    __shared__ float thr[RBTOK];
    __shared__ float e2s[CHUNK];

    const int tid  = threadIdx.x;
    const int lane = tid & 63;
    const int w    = tid >> 6;

    if (tid < RBTOK) {
        int s = (tid < nt) ? tid : (nt - 1);
        int t = clist[base + s];
        tls[tid] = t;
        thr[tid] = (tid < nt) ? (m1f[t] - CAND_MM) : FLT_MAX;
    }
    __syncthreads();

    const int l31 = lane & 31, hh = lane >> 5;
    const float mythr = thr[l31];
    const int   mytok = tls[l31];
    const int swz = (l31 >> 1) & 3;
    const int arow = (w * 32 + l31) * 32;
    const int brow = l31 * 32;
    const int a0 = arow + ((hh ^ swz) << 3);
    const int a1 = arow + (((2 + hh) ^ swz) << 3);
    const int b0 = brow + ((hh ^ swz) << 3);
    const int b1 = brow + (((2 + hh) ^ swz) << 3);

    // e staging: 2 slots/thread (pure copies); z: tid<128, one slot each (hi+lo)
    const int er0 = tid >> 2, eq0 = tid & 3;
    const int er1 = er0 + 64;
    const int eso0 = er0 * 32 + ((eq0 ^ ((er0 >> 1) & 3)) << 3);
    const int eso1 = er1 * 32 + ((eq0 ^ ((er1 >> 1) & 3)) << 3);
    const int zr = (tid & 127) >> 2, zq = tid & 3;
    const int zso = zr * 32 + ((zq ^ ((zr >> 1) & 3)) << 3);

    for (int c = 0; c < RSPLIT / CHUNK; c++) {
        const int code0 = sp * RSPLIT + c * CHUNK;
        const float e2v = (tid < CHUNK) ? e2h[code0 + tid] : 0.f;
        f32x16 acc;
        #pragma unroll
        for (int r = 0; r < 16; r++) acc[r] = 0.f;

        for (int st = 0; st < 8; st++) {
            const int d0 = st * 32;
            const size_t ei0 = ((size_t)(code0 + er0) << 8) + d0 + (eq0 << 3);
            const size_t ei1 = ((size_t)(code0 + er1) << 8) + d0 + (eq0 << 3);
            bf16x8 eh0 = *(const bf16x8*)(ehi + ei0);
            bf16x8 el0 = *(const bf16x8*)(elo + ei0);
            bf16x8 eh1 = *(const bf16x8*)(ehi + ei1);
            bf16x8 el1 = *(const bf16x8*)(elo + ei1);
            bf16x8 zh = {}, zl = {};
            if (tid < 128) {
                const size_t zi = ((size_t)tls[zr] << 8) + d0 + (zq << 3);
                zh = *(const bf16x8*)(zhi + zi);
                float4 za = *(const float4*)(zf + zi);
                float4 zb = *(const float4*)(zf + zi + 4);
                zl = lo8(zh, za, zb);
            }
            __syncthreads();
            *(bf16x8*)(rsm + R_ESH + eso0) = eh0;
            *(bf16x8*)(rsm + R_ESL + eso0) = el0;
            *(bf16x8*)(rsm + R_ESH + eso1) = eh1;
            *(bf16x8*)(rsm + R_ESL + eso1) = el1;
            if (tid < 128) {
                *(bf16x8*)(rsm + R_ZSH + zso) = zh;
                *(bf16x8*)(rsm + R_ZSL + zso) = zl;
            }
            if (st == 0 && tid < CHUNK) e2s[tid] = e2v;
            __syncthreads();
            {
                bf16x8 ah = *(const bf16x8*)(rsm + R_ESH + a0);
                bf16x8 al = *(const bf16x8*)(rsm + R_ESL + a0);
                bf16x8 bh = *(const bf16x8*)(rsm + R_ZSH + b0);
                bf16x8 bl = *(const bf16x8*)(rsm + R_ZSL + b0);
                MFMA3(acc, ah, al, bh, bl);
            }
            {
                bf16x8 ah = *(const bf16x8*)(rsm + R_ESH + a1);
                bf16x8 al = *(const bf16x8*)(rsm + R_ESL + a1);
                bf16x8 bh = *(const bf16x8*)(rsm + R_ZSH + b1);
                bf16x8 bl = *(const bf16x8*)(rsm + R_ZSL + b1);
                MFMA3(acc, ah, al, bh, bl);
            }
        }
        #pragma unroll
        for (int r = 0; r < 16; r++) {
            const int local = w * 32 + hh * 4 + (r & 3) + ((r >> 2) << 3);
            float a = acc[r] - e2s[local];
            if (a >= mythr) {
                unsigned p = atomicAdd(&ccnt_g[mytok], 1u);
                if (p < MAXCAND) cand_g[(size_t)mytok * MAXCAND + p] = code0 + local;
            }
        }
    }
}

// ---------------- resolve: np-exact d over candidates, first-index min ----------------
__global__ __launch_bounds__(256) void resolve_kernel(
    const float* __restrict__ z, const float* __restrict__ emb,
    const float* __restrict__ e2np, const float* __restrict__ Cnp,
    const unsigned* __restrict__ ccount, const int* __restrict__ clist,
    const unsigned* __restrict__ ccnt_g, const int* __restrict__ cand_g,
    int* __restrict__ idxf)
{
    const unsigned count = *ccount;
    const int lane = threadIdx.x & 63;
    const int w    = threadIdx.x >> 6;
    for (unsigned c = blockIdx.x * 4 + w; c < count; c += gridDim.x * 4) {
        const int t = clist[c];
        const int n = (int)min(ccnt_g[t], (unsigned)MAXCAND);
        float bd = FLT_MAX; int bk = 0x7fffffff;
        if (lane < n) {
            const int k = cand_g[(size_t)t * MAXCAND + lane];
            float g = np_einsum256(z + (size_t)t * D_DIM, emb + (size_t)k * D_DIM);
            bd = np_dtilde(Cnp[t], e2np[k], g);
            bk = k;
        }
        #pragma unroll
        for (int off = 32; off >= 1; off >>= 1) {
            float od = __shfl_xor(bd, off);
            int   ok = __shfl_xor(bk, off);
            if (od < bd || (od == bd && ok < bk)) { bd = od; bk = ok; }
        }
        if (lane == 0 && n > 0) idxf[t] = bk;
    }
}

// ---------------- gather z_q, write out0, fp64 MSE sum ----------------
__global__ __launch_bounds__(256) void out_loss_kernel(
    const float* __restrict__ z, const float* __restrict__ emb,
    const int* __restrict__ idxf, float* __restrict__ out0,
    double* __restrict__ loss_sum)
{
    const int total4 = N_TOK * (D_DIM / 4);
    double lsum = 0.0;
    for (int p = blockIdx.x * 256 + threadIdx.x; p < total4; p += gridDim.x * 256) {
        const int n  = p >> 6;
        const int d4 = p & 63;
        const int k  = idxf[n];
        float4 zv = ((const float4*)z)[p];
        float4 ev = ((const float4*)(emb + (size_t)k * D_DIM))[d4];
        float dx = ev.x - zv.x, dy = ev.y - zv.y,
              dz = ev.z - zv.z, dw = ev.w - zv.w;
        float4 o;
        o.x = zv.x + dx; o.y = zv.y + dy; o.z = zv.z + dz; o.w = zv.w + dw;
        ((float4*)out0)[p] = o;
        lsum += (double)dx * dx + (double)dy * dy
              + (double)dz * dz + (double)dw * dw;
    }
    #pragma unroll
    for (int off = 32; off >= 1; off >>= 1) lsum += __shfl_xor(lsum, off);
    __shared__ double wsum[4];
    const int wv = threadIdx.x >> 6;
    if ((threadIdx.x & 63) == 0) wsum[wv] = lsum;
    __syncthreads();
    if (threadIdx.x == 0)
        atomicAdd(loss_sum, wsum[0] + wsum[1] + wsum[2] + wsum[3]);
}

__global__ __launch_bounds__(256) void finalize_kernel(
    const int* __restrict__ idxf, const double* __restrict__ loss_sum,
    float* __restrict__ out)
{
    const int t = blockIdx.x * 256 + threadIdx.x;
    if (t < N_TOK) out[8388611 + t] = (float)idxf[t];
    if (t == 0) {
        double mse = *loss_sum * (1.0 / 8388608.0);
        out[8388608] = (float)(1.25 * mse);
        out[8388609] = (float)(0.25 * mse);
        out[8388610] = (float)mse;
    }
}

extern "C" void kernel_launch(void* const* d_in, const int* in_sizes, int n_in,
                              void* d_out, int out_size, void* d_ws, size_t ws_size,
                              hipStream_t stream)
{
    const float* z   = (const float*)d_in[0];
    const float* emb = (const float*)d_in[1];
    float* out = (float*)d_out;
    char*  ws  = (char*)d_ws;
    char*  ob  = (char*)d_out;

    // big scratch inside d_out (all reads finish before out_loss/finalize rewrite it)
    short*    ehi    = (short*)(ob + 0);
    short*    elo    = (short*)(ob + 4194304);
    short*    zhi    = (short*)(ob + 8388608);
    float*    m1a    = (float*)(ob + 25165824);
    float*    m2a    = (float*)(ob + 25690112);
    int*      i1a    = (int*)(ob + 26214400);
    int*      cand_g = (int*)(ob + 26738688);

    double*   loss_sum = (double*)(ws + 0);
    unsigned* ccount   = (unsigned*)(ws + 8);
    float*    e2np     = (float*)(ws + 16);
    float*    e2h      = (float*)(ws + 32784);
    float*    Cnp      = (float*)(ws + 65552);
    float*    m1f      = (float*)(ws + 196624);
    int*      idxf     = (int*)(ws + 327696);
    int*      clist    = (int*)(ws + 458768);
    unsigned* ccnt_g   = (unsigned*)(ws + 589840);

    prep_e_kernel<<<dim3(K_CODES / 256), dim3(256), 0, stream>>>(
        emb, e2np, e2h, ccount, loss_sum);
    prep_z_kernel<<<dim3(N_TOK / 256), dim3(256), 0, stream>>>(z, Cnp);
    cvt_e_kernel<<<dim3(K_CODES * D_DIM / 8 / 256), dim3(256), 0, stream>>>(emb, ehi, elo);
    cvt_zhi_kernel<<<dim3(N_TOK * D_DIM / 8 / 256), dim3(256), 0, stream>>>(z, zhi);
    bulk_kernel<<<dim3((N_TOK / BTOK) * NSPLIT), dim3(256), 0, stream>>>(
        z, zhi, ehi, elo, e2h, m1a, m2a, i1a);
    merge_kernel<<<dim3(N_TOK / 256), dim3(256), 0, stream>>>(
        m1a, m2a, i1a, m1f, idxf, clist, ccount, ccnt_g);
    rescue_kernel<<<dim3(N_TOK / RBTOK, NRS), dim3(256), 0, stream>>>(
        z, zhi, ehi, elo, e2h, m1f, ccount, clist, ccnt_g, cand_g);
    resolve_kernel<<<dim3(128), dim3(256), 0, stream>>>(
        z, emb, e2np, Cnp, ccount, clist, ccnt_g, cand_g, idxf);
    out_loss_kernel<<<dim3(1024), dim3(256), 0, stream>>>(
        z, emb, idxf, out, loss_sum);
    finalize_kernel<<<dim3(N_TOK / 256), dim3(256), 0, stream>>>(
        idxf, loss_sum, out);
}